// Round 2
// baseline (14526.141 us; speedup 1.0000x reference)
//
#include <hip/hip_runtime.h>
#include <math.h>

// ---------------- activations ----------------
#define ACT_NONE 0
#define ACT_GELU 1
#define ACT_SOFTPLUS 2

template<int ACT>
__device__ __forceinline__ float act_apply(float x){
  if (ACT == ACT_GELU)     return 0.5f * x * (1.0f + erff(x * 0.70710678118654752f));
  if (ACT == ACT_SOFTPLUS) return fmaxf(x, 0.0f) + log1pf(expf(-fabsf(x)));
  return x;
}

// ---------------- GEMM 128x128 tile, 256 thr, 8x8/thread, Ktile=16 ----------------
template<int ACT, int ACC>
__global__ __launch_bounds__(256) void gemm128_kernel(
    const float* __restrict__ A, const float* __restrict__ W,
    const float* __restrict__ bias, float* __restrict__ C,
    int K, int lda, int ldw, int ldc)
{
  __shared__ float As[16][128];
  __shared__ float Ws[16][128];
  const int tid = threadIdx.x;
  const int m0 = blockIdx.y * 128;
  const int n0 = blockIdx.x * 128;
  const int tx = tid & 15, ty = tid >> 4;
  const int ar = tid >> 2, ak = (tid & 3) * 4;
  const int wk = tid >> 5, wn = (tid & 31) * 4;

  float acc[8][8];
#pragma unroll
  for (int i = 0; i < 8; i++)
#pragma unroll
    for (int j = 0; j < 8; j++) acc[i][j] = 0.0f;

  for (int k0 = 0; k0 < K; k0 += 16) {
    float4 a0 = *(const float4*)(A + (size_t)(m0 + ar)      * lda + k0 + ak);
    float4 a1 = *(const float4*)(A + (size_t)(m0 + ar + 64) * lda + k0 + ak);
    float4 w0 = *(const float4*)(W + (size_t)(k0 + wk)     * ldw + n0 + wn);
    float4 w1 = *(const float4*)(W + (size_t)(k0 + wk + 8) * ldw + n0 + wn);
    __syncthreads();
    As[ak + 0][ar] = a0.x; As[ak + 1][ar] = a0.y; As[ak + 2][ar] = a0.z; As[ak + 3][ar] = a0.w;
    As[ak + 0][ar + 64] = a1.x; As[ak + 1][ar + 64] = a1.y; As[ak + 2][ar + 64] = a1.z; As[ak + 3][ar + 64] = a1.w;
    *(float4*)&Ws[wk][wn] = w0;
    *(float4*)&Ws[wk + 8][wn] = w1;
    __syncthreads();
#pragma unroll
    for (int k = 0; k < 16; k++) {
      float4 xa = *(float4*)&As[k][ty * 8];
      float4 xb = *(float4*)&As[k][ty * 8 + 4];
      float4 y0 = *(float4*)&Ws[k][tx * 8];
      float4 y1 = *(float4*)&Ws[k][tx * 8 + 4];
      float a8[8] = {xa.x, xa.y, xa.z, xa.w, xb.x, xb.y, xb.z, xb.w};
      float b8[8] = {y0.x, y0.y, y0.z, y0.w, y1.x, y1.y, y1.z, y1.w};
#pragma unroll
      for (int i = 0; i < 8; i++)
#pragma unroll
        for (int j = 0; j < 8; j++) acc[i][j] = fmaf(a8[i], b8[j], acc[i][j]);
    }
  }
#pragma unroll
  for (int i = 0; i < 8; i++) {
    float* cp = C + (size_t)(m0 + ty * 8 + i) * ldc + n0 + tx * 8;
    float v[8];
#pragma unroll
    for (int j = 0; j < 8; j++) {
      float t = acc[i][j];
      if (bias) t += bias[n0 + tx * 8 + j];
      t = act_apply<ACT>(t);
      if (ACC) t += cp[j];
      v[j] = t;
    }
    *(float4*)cp       = make_float4(v[0], v[1], v[2], v[3]);
    *(float4*)(cp + 4) = make_float4(v[4], v[5], v[6], v[7]);
  }
}

// ---------------- GEMM 64x64 tile, 256 thr, 4x4/thread ----------------
template<int ACT>
__global__ __launch_bounds__(256) void gemm64_kernel(
    const float* __restrict__ A, const float* __restrict__ W,
    const float* __restrict__ bias, float* __restrict__ C,
    int K, int lda, int ldw, int ldc)
{
  __shared__ float As[16][64];
  __shared__ float Ws[16][64];
  const int tid = threadIdx.x;
  const int m0 = blockIdx.y * 64;
  const int n0 = blockIdx.x * 64;
  const int tx = tid & 15, ty = tid >> 4;
  const int ar = tid >> 2, ak = (tid & 3) * 4;
  const int wk = tid >> 4, wn = (tid & 15) * 4;

  float acc[4][4];
#pragma unroll
  for (int i = 0; i < 4; i++)
#pragma unroll
    for (int j = 0; j < 4; j++) acc[i][j] = 0.0f;

  for (int k0 = 0; k0 < K; k0 += 16) {
    float4 a0 = *(const float4*)(A + (size_t)(m0 + ar) * lda + k0 + ak);
    float4 w0 = *(const float4*)(W + (size_t)(k0 + wk) * ldw + n0 + wn);
    __syncthreads();
    As[ak + 0][ar] = a0.x; As[ak + 1][ar] = a0.y; As[ak + 2][ar] = a0.z; As[ak + 3][ar] = a0.w;
    *(float4*)&Ws[wk][wn] = w0;
    __syncthreads();
#pragma unroll
    for (int k = 0; k < 16; k++) {
      float4 xa = *(float4*)&As[k][ty * 4];
      float4 yb = *(float4*)&Ws[k][tx * 4];
      float a4[4] = {xa.x, xa.y, xa.z, xa.w};
      float b4[4] = {yb.x, yb.y, yb.z, yb.w};
#pragma unroll
      for (int i = 0; i < 4; i++)
#pragma unroll
        for (int j = 0; j < 4; j++) acc[i][j] = fmaf(a4[i], b4[j], acc[i][j]);
    }
  }
#pragma unroll
  for (int i = 0; i < 4; i++) {
    float* cp = C + (size_t)(m0 + ty * 4 + i) * ldc + n0 + tx * 4;
    float v[4];
#pragma unroll
    for (int j = 0; j < 4; j++) {
      float t = acc[i][j];
      if (bias) t += bias[n0 + tx * 4 + j];
      v[j] = act_apply<ACT>(t);
    }
    *(float4*)cp = make_float4(v[0], v[1], v[2], v[3]);
  }
}

// ---------------- misc elementwise ----------------
__global__ __launch_bounds__(256) void add_pos_kernel(float* __restrict__ X, const float* __restrict__ pos){
  int i = blockIdx.x * 256 + threadIdx.x;
  X[i] += pos[((i >> 8) & 63) * 256 + (i & 255)];
}

// ---------------- fused attention (scores + softmax + PV), one block per (n,h) ---
// block = 64 threads. QKVc: chunk-local [128][64][768]. ATTOc: [128][64][256].
__global__ __launch_bounds__(64) void attn_fused_kernel(
    const float* __restrict__ QKVc, const float* __restrict__ mask,
    float* __restrict__ ATTOc, int n0)
{
  int bid = blockIdx.x;
  int nl = bid >> 3;          // chunk-local sequence
  int h = bid & 7;
  int n = n0 + nl;            // global sequence (for mask)
  int tid = threadIdx.x;
  int tx = tid & 7, ty = tid >> 3;
  __shared__ float Qt[32][68];
  __shared__ float Kt[32][68];
  __shared__ float Vs[64][36];
  __shared__ float Pt[64][68];   // Pt[key][query]
  __shared__ float bs[64];
  const float* base = QKVc + (size_t)nl * (64 * 768);
#pragma unroll
  for (int i = 0; i < 32; i++) {
    int idx = tid + i * 64;
    int bar = idx >> 5, c = idx & 31;
    Qt[c][bar] = base[bar * 768 + h * 32 + c];
    Kt[c][bar] = base[bar * 768 + 256 + h * 32 + c];
    Vs[bar][c] = base[bar * 768 + 512 + h * 32 + c];
  }
  bs[tid] = (1.0f - mask[n * 64 + tid]) * -1e9f;
  __syncthreads();
  float acc[8][8] = {};
  for (int c = 0; c < 32; c++) {
    float4 ax = *(float4*)&Qt[c][ty * 8];
    float4 ay = *(float4*)&Qt[c][ty * 8 + 4];
    float4 bx = *(float4*)&Kt[c][tx * 8];
    float4 by = *(float4*)&Kt[c][tx * 8 + 4];
    float a8[8] = {ax.x, ax.y, ax.z, ax.w, ay.x, ay.y, ay.z, ay.w};
    float b8[8] = {bx.x, bx.y, bx.z, bx.w, by.x, by.y, by.z, by.w};
#pragma unroll
    for (int i = 0; i < 8; i++)
#pragma unroll
      for (int j = 0; j < 8; j++) acc[i][j] = fmaf(a8[i], b8[j], acc[i][j]);
  }
  const float scale = 0.17677669529663687f;
#pragma unroll
  for (int i = 0; i < 8; i++) {
    float s[8];
    float mx = -3.0e38f;
#pragma unroll
    for (int j = 0; j < 8; j++) { s[j] = acc[i][j] * scale + bs[tx * 8 + j]; mx = fmaxf(mx, s[j]); }
#pragma unroll
    for (int off = 1; off < 8; off <<= 1) mx = fmaxf(mx, __shfl_xor(mx, off));
    float sum = 0.0f;
#pragma unroll
    for (int j = 0; j < 8; j++) { s[j] = expf(s[j] - mx); sum += s[j]; }
#pragma unroll
    for (int off = 1; off < 8; off <<= 1) sum += __shfl_xor(sum, off);
    float inv = 1.0f / sum;
#pragma unroll
    for (int j = 0; j < 8; j++) Pt[tx * 8 + j][ty * 8 + i] = s[j] * inv;
  }
  __syncthreads();
  float o[8][4] = {};
  for (int j = 0; j < 64; j++) {
    float4 px = *(float4*)&Pt[j][ty * 8];
    float4 py = *(float4*)&Pt[j][ty * 8 + 4];
    float4 v  = *(float4*)&Vs[j][tx * 4];
    float p8[8] = {px.x, px.y, px.z, px.w, py.x, py.y, py.z, py.w};
#pragma unroll
    for (int i = 0; i < 8; i++) {
      o[i][0] = fmaf(p8[i], v.x, o[i][0]);
      o[i][1] = fmaf(p8[i], v.y, o[i][1]);
      o[i][2] = fmaf(p8[i], v.z, o[i][2]);
      o[i][3] = fmaf(p8[i], v.w, o[i][3]);
    }
  }
#pragma unroll
  for (int i = 0; i < 8; i++) {
    float* op = ATTOc + (size_t)(nl * 64 + ty * 8 + i) * 256 + h * 32 + tx * 4;
    *(float4*)op = make_float4(o[i][0], o[i][1], o[i][2], o[i][3]);
  }
}

// ---------------- LayerNorm (wave per row) ----------------
// MODE 0: o = LN(a+b)*g+beta     MODE 1: o = LN(a)*g+beta + b
template<int MODE>
__global__ __launch_bounds__(256) void ln_kernel(
    const float* __restrict__ a, const float* __restrict__ b,
    const float* __restrict__ g, const float* __restrict__ beta,
    float* __restrict__ o, int Wd)
{
  int wave = threadIdx.x >> 6;
  int lane = threadIdx.x & 63;
  int row = blockIdx.x * 4 + wave;
  int P = Wd >> 6;
  const float* ar = a + (size_t)row * Wd;
  const float* br = b + (size_t)row * Wd;
  float v[8];
  float s = 0.0f;
  for (int i = 0; i < P; i++) {
    float x = ar[lane + i * 64];
    if (MODE == 0) x += br[lane + i * 64];
    v[i] = x; s += x;
  }
#pragma unroll
  for (int off = 32; off; off >>= 1) s += __shfl_xor(s, off);
  float mean = s / Wd;
  float vs = 0.0f;
  for (int i = 0; i < P; i++) { float d = v[i] - mean; vs += d * d; }
#pragma unroll
  for (int off = 32; off; off >>= 1) vs += __shfl_xor(vs, off);
  float rstd = rsqrtf(vs / Wd + 1e-5f);
  for (int i = 0; i < P; i++) {
    int col = lane + i * 64;
    float t = (v[i] - mean) * rstd * g[col] + beta[col];
    if (MODE == 1) t += br[col];
    o[(size_t)row * Wd + col] = t;
  }
}

// ---------------- masked mean over bars ----------------
__global__ __launch_bounds__(256) void mean_kernel(
    const float* __restrict__ X, const float* __restrict__ mask, float* __restrict__ FE)
{
  int n = blockIdx.x;
  int c = threadIdx.x;
  float s = 0.0f, ms = 0.0f;
  for (int bar = 0; bar < 64; bar++) {
    float mk = mask[n * 64 + bar];
    s = fmaf(X[(size_t)(n * 64 + bar) * 256 + c], mk, s);
    ms += mk;
  }
  FE[n * 256 + c] = s / fmaxf(ms, 1.0f);
}

// ---------------- mamba conv (4-tap causal) + silu ----------------
__global__ __launch_bounds__(256) void conv_kernel(
    const float* __restrict__ XZ, const float* __restrict__ w,
    const float* __restrict__ b, float* __restrict__ XC)
{
  int idx = blockIdx.x * 256 + threadIdx.x;
  int t = idx >> 10, c = idx & 1023;
  float acc = b[c];
  const float* wc = w + c * 4;
#pragma unroll
  for (int k = 0; k < 4; k++) {
    int tt = t + k - 3;
    if (tt >= 0) acc = fmaf(XZ[(size_t)tt * 2048 + c], wc[k], acc);
  }
  XC[idx] = acc / (1.0f + expf(-acc));
}

// ---------------- chunked scan (32 chunks x 32 steps) ----------------
#define NCH 32
#define CLEN 32

__global__ __launch_bounds__(256) void scan1_kernel(
    const float* __restrict__ DT, const float* __restrict__ XC,
    const float* __restrict__ XDBL, const float* __restrict__ Alog,
    float* __restrict__ HEND, float* __restrict__ PPR)
{
  int j = blockIdx.x >> 2;
  int c = (blockIdx.x & 3) * 256 + threadIdx.x;
  int t0 = j * CLEN;
  __shared__ float Bs[CLEN][16];
  for (int i = threadIdx.x; i < CLEN * 16; i += 256) {
    int r = i >> 4, s = i & 15;
    Bs[r][s] = XDBL[(t0 + r) * 64 + 32 + s];
  }
  float A[16], h[16], Pp[16];
#pragma unroll
  for (int s = 0; s < 16; s++) {
    A[s] = -expf(Alog[c * 16 + s]);
    h[s] = 0.0f; Pp[s] = 1.0f;
  }
  __syncthreads();
  for (int tt = 0; tt < CLEN; tt++) {
    int t = t0 + tt;
    float dtv = DT[(size_t)t * 1024 + c];
    float u = dtv * XC[(size_t)t * 1024 + c];
#pragma unroll
    for (int s = 0; s < 16; s++) {
      float e = expf(dtv * A[s]);
      h[s] = fmaf(h[s], e, u * Bs[tt][s]);
      Pp[s] *= e;
    }
  }
#pragma unroll
  for (int s = 0; s < 16; s++) {
    HEND[(size_t)(j * 1024 + c) * 16 + s] = h[s];
    PPR [(size_t)(j * 1024 + c) * 16 + s] = Pp[s];
  }
}

__global__ __launch_bounds__(256) void scan2_kernel(
    const float* __restrict__ HEND, const float* __restrict__ PPR, float* __restrict__ CIN)
{
  int id = blockIdx.x * 256 + threadIdx.x;
  float carry = 0.0f;
  for (int j = 0; j < NCH; j++) {
    CIN[j * 16384 + id] = carry;
    carry = fmaf(PPR[j * 16384 + id], carry, HEND[j * 16384 + id]);
  }
}

__global__ __launch_bounds__(256) void scan3_kernel(
    const float* __restrict__ DT, const float* __restrict__ XC,
    const float* __restrict__ XDBL, const float* __restrict__ Alog,
    const float* __restrict__ CIN, const float* __restrict__ mD,
    const float* __restrict__ XZ, float* __restrict__ Y)
{
  int j = blockIdx.x >> 2;
  int c = (blockIdx.x & 3) * 256 + threadIdx.x;
  int t0 = j * CLEN;
  __shared__ float Bs[CLEN][16], Cs[CLEN][16];
  for (int i = threadIdx.x; i < CLEN * 16; i += 256) {
    int r = i >> 4, s = i & 15;
    Bs[r][s] = XDBL[(t0 + r) * 64 + 32 + s];
    Cs[r][s] = XDBL[(t0 + r) * 64 + 48 + s];
  }
  float A[16], h[16];
#pragma unroll
  for (int s = 0; s < 16; s++) {
    A[s] = -expf(Alog[c * 16 + s]);
    h[s] = CIN[(size_t)(j * 1024 + c) * 16 + s];
  }
  float dval = mD[c];
  __syncthreads();
  for (int tt = 0; tt < CLEN; tt++) {
    int t = t0 + tt;
    float dtv = DT[(size_t)t * 1024 + c];
    float xcv = XC[(size_t)t * 1024 + c];
    float u = dtv * xcv;
    float y = 0.0f;
#pragma unroll
    for (int s = 0; s < 16; s++) {
      float e = expf(dtv * A[s]);
      h[s] = fmaf(h[s], e, u * Bs[tt][s]);
      y = fmaf(h[s], Cs[tt][s], y);
    }
    float z = XZ[(size_t)t * 2048 + 1024 + c];
    float sz = z / (1.0f + expf(-z));
    Y[(size_t)t * 1024 + c] = (y + dval * xcv) * sz;
  }
}

// ---------------- pooling + head ----------------
__global__ __launch_bounds__(1024) void pool1_kernel(
    const float* __restrict__ XM, const float* __restrict__ pw,
    const float* __restrict__ pb, float* __restrict__ PW)
{
  int t = threadIdx.x;
  float s = pb[0];
  for (int i = 0; i < 512; i++) s = fmaf(XM[(size_t)t * 512 + i], pw[i], s);
  __shared__ float red[1024];
  red[t] = s;
  __syncthreads();
  for (int off = 512; off > 0; off >>= 1) {
    if (t < off) red[t] = fmaxf(red[t], red[t + off]);
    __syncthreads();
  }
  float mx = red[0];
  __syncthreads();
  float e = expf(s - mx);
  red[t] = e;
  __syncthreads();
  for (int off = 512; off > 0; off >>= 1) {
    if (t < off) red[t] = red[t] + red[t + off];
    __syncthreads();
  }
  PW[t] = e / red[0];
}

__global__ __launch_bounds__(256) void pool2_kernel(
    const float* __restrict__ XM, const float* __restrict__ PW, float* __restrict__ HP)
{
  int hcol = blockIdx.x * 256 + threadIdx.x;
  float s = 0.0f;
  for (int tn = 0; tn < 1024; tn++) s = fmaf(PW[tn], XM[(size_t)tn * 512 + hcol], s);
  HP[hcol] = s;
}

__device__ __forceinline__ float blk_reduce_sum_128(float v, float* red){
  int t = threadIdx.x;
#pragma unroll
  for (int off = 32; off; off >>= 1) v += __shfl_xor(v, off);
  __syncthreads();
  if ((t & 63) == 0) red[t >> 6] = v;
  __syncthreads();
  return red[0] + red[1];
}

__global__ __launch_bounds__(128) void head_kernel(
    const float* __restrict__ HP, const float* __restrict__ h1w, const float* __restrict__ h1b,
    const float* __restrict__ g1, const float* __restrict__ be1,
    const float* __restrict__ h2w, const float* __restrict__ h2b,
    const float* __restrict__ g2, const float* __restrict__ be2,
    const float* __restrict__ h3w, const float* __restrict__ h3b,
    float* __restrict__ out)
{
  __shared__ float t1[128];
  __shared__ float red[2];
  int i = threadIdx.x;
  float s = h1b[i];
  for (int k = 0; k < 512; k++) s = fmaf(HP[k], h1w[k * 128 + i], s);
  float mean = blk_reduce_sum_128(s, red) * (1.0f / 128.0f);
  float d = s - mean;
  float var = blk_reduce_sum_128(d * d, red) * (1.0f / 128.0f);
  float x1 = d * rsqrtf(var + 1e-5f) * g1[i] + be1[i];
  x1 = 0.5f * x1 * (1.0f + erff(x1 * 0.70710678118654752f));
  t1[i] = x1;
  __syncthreads();
  s = h2b[i];
  for (int k = 0; k < 128; k++) s = fmaf(t1[k], h2w[k * 128 + i], s);
  mean = blk_reduce_sum_128(s, red) * (1.0f / 128.0f);
  d = s - mean;
  var = blk_reduce_sum_128(d * d, red) * (1.0f / 128.0f);
  float x2 = d * rsqrtf(var + 1e-5f) * g2[i] + be2[i];
  x2 = 0.5f * x2 * (1.0f + erff(x2 * 0.70710678118654752f));
  float tot = blk_reduce_sum_128(x2 * h3w[i], red);
  if (i == 0) out[0] = tot + h3b[0];
}

__global__ __launch_bounds__(256) void copyx_kernel(const float* __restrict__ XM, float* __restrict__ out){
  int i = blockIdx.x * 256 + threadIdx.x;
  out[1 + i] = XM[i];
}

// ---------------- launch ----------------
extern "C" void kernel_launch(void* const* d_in, const int* in_sizes, int n_in,
                              void* d_out, int out_size, void* d_ws, size_t ws_size,
                              hipStream_t stream)
{
  const float* frames   = (const float*)d_in[0];
  const float* fmask    = (const float*)d_in[1];
  const float* in_w     = (const float*)d_in[2];
  const float* in_b     = (const float*)d_in[3];
  const float* pos_emb  = (const float*)d_in[4];
  const float* qkv_w    = (const float*)d_in[5];
  const float* qkv_b    = (const float*)d_in[6];
  const float* ao_w     = (const float*)d_in[7];
  const float* ao_b     = (const float*)d_in[8];
  const float* ln1_g    = (const float*)d_in[9];
  const float* ln1_b    = (const float*)d_in[10];
  const float* ffn_w1   = (const float*)d_in[11];
  const float* ffn_b1   = (const float*)d_in[12];
  const float* ffn_w2   = (const float*)d_in[13];
  const float* ffn_b2   = (const float*)d_in[14];
  const float* ln2_g    = (const float*)d_in[15];
  const float* ln2_b    = (const float*)d_in[16];
  const float* proj_w   = (const float*)d_in[17];
  const float* proj_b   = (const float*)d_in[18];
  const float* m_in_w   = (const float*)d_in[19];
  const float* m_conv_w = (const float*)d_in[20];
  const float* m_conv_b = (const float*)d_in[21];
  const float* m_xproj_w= (const float*)d_in[22];
  const float* m_dt_w   = (const float*)d_in[23];
  const float* m_dt_b   = (const float*)d_in[24];
  const float* m_Alog   = (const float*)d_in[25];
  const float* m_D      = (const float*)d_in[26];
  const float* m_out_w  = (const float*)d_in[27];
  const float* m_ln_g   = (const float*)d_in[28];
  const float* m_ln_b   = (const float*)d_in[29];
  const float* pool_w   = (const float*)d_in[30];
  const float* pool_b   = (const float*)d_in[31];
  const float* h1_w     = (const float*)d_in[32];
  const float* h1_b     = (const float*)d_in[33];
  const float* hg1      = (const float*)d_in[34];
  const float* hb1      = (const float*)d_in[35];
  const float* h2_w     = (const float*)d_in[36];
  const float* h2_b     = (const float*)d_in[37];
  const float* hg2      = (const float*)d_in[38];
  const float* hb2      = (const float*)d_in[39];
  const float* h3_w     = (const float*)d_in[40];
  const float* h3_b     = (const float*)d_in[41];
  float* out = (float*)d_out;

  // ---- workspace layout: 28,052,480 floats = 112.2 MB ----
  float* ws = (float*)d_ws;
  float* X  = ws;                  // 16,777,216  (65536 x 256) persistent encoder state
  float* QF = X + 16777216;        //  6,291,456  QKV chunk (8192x768) / FFN chunk (8192x512)
  float* AT = QF + 6291456;        //  2,097,152  attn out chunk (8192x256)
  float* RC = AT + 2097152;        //  2,097,152  residual chunk (8192x256)
  float* FE = RC + 2097152;        //    262,144  frame_emb (1024x256)
  float* XM = FE + 262144;         //    524,288  mamba state (1024x512)
  float* PW = XM + 524288;         //      2,048
  float* HP = PW + 2048;           //      1,024

  // mamba aliases: reuse QF..QF+10,485,760 (QF+AT+RC region, encoder done)
  float* XZ   = QF;                // 2,097,152  (1024x2048)
  float* XC   = QF + 2097152;      // 1,048,576
  float* DT   = QF + 3145728;      // 1,048,576
  float* XDBL = QF + 4194304;      //    65,536
  float* Y    = QF + 4259840;      // 1,048,576
  float* TMP  = QF + 5308416;      //   524,288
  float* HEND = QF + 5832704;      //   524,288
  float* PPR  = QF + 6356992;      //   524,288
  float* CIN  = QF + 6881280;      //   524,288  (ends at 7,405,568)

  // stage A: x = frames @ in_w + in_b + pos_emb   (full 65536 rows)
  gemm128_kernel<ACT_NONE,0><<<dim3(2,512),256,0,stream>>>(frames, in_w, in_b, X, 32, 32, 256, 256);
  add_pos_kernel<<<65536,256,0,stream>>>(X, pos_emb);

  // encoder: 8 chunks of 128 sequences (8192 rows) each
  for (int l = 0; l < 4; l++) {
    for (int ch = 0; ch < 8; ch++) {
      size_t roff = (size_t)ch * 8192 * 256;
      // QKV for chunk
      gemm128_kernel<ACT_NONE,0><<<dim3(6,64),256,0,stream>>>(
          X + roff, qkv_w + (size_t)l*256*768, qkv_b + l*768, QF, 256, 256, 768, 768);
      // fused attention
      attn_fused_kernel<<<1024,64,0,stream>>>(QF, fmask, AT, ch * 128);
      // out-proj
      gemm128_kernel<ACT_NONE,0><<<dim3(2,64),256,0,stream>>>(
          AT, ao_w + (size_t)l*256*256, ao_b + l*256, RC, 256, 256, 256, 256);
      // ln1 (chunk rows)
      ln_kernel<0><<<2048,256,0,stream>>>(X + roff, RC, ln1_g + l*256, ln1_b + l*256, X + roff, 256);
      // FFN (two column halves into QF, consumed immediately)
      for (int half = 0; half < 2; half++) {
        gemm128_kernel<ACT_GELU,0><<<dim3(4,64),256,0,stream>>>(
            X + roff, ffn_w1 + (size_t)l*256*1024 + half*512, ffn_b1 + l*1024 + half*512, QF, 256, 256, 1024, 512);
        if (half == 0)
          gemm128_kernel<ACT_NONE,0><<<dim3(2,64),256,0,stream>>>(
              QF, ffn_w2 + (size_t)l*1024*256, ffn_b2 + l*256, RC, 512, 512, 256, 256);
        else
          gemm128_kernel<ACT_NONE,1><<<dim3(2,64),256,0,stream>>>(
              QF, ffn_w2 + (size_t)l*1024*256 + 512*256, nullptr, RC, 512, 512, 256, 256);
      }
      // ln2 (chunk rows)
      ln_kernel<0><<<2048,256,0,stream>>>(X + roff, RC, ln2_g + l*256, ln2_b + l*256, X + roff, 256);
    }
  }

  mean_kernel<<<1024,256,0,stream>>>(X, fmask, FE);
  gemm64_kernel<ACT_NONE><<<dim3(8,16),256,0,stream>>>(FE, proj_w, proj_b, XM, 256, 256, 512, 512);

  for (int l = 0; l < 8; l++) {
    gemm64_kernel<ACT_NONE><<<dim3(32,16),256,0,stream>>>(
        XM, m_in_w + (size_t)l*512*2048, nullptr, XZ, 512, 512, 2048, 2048);
    conv_kernel<<<4096,256,0,stream>>>(XZ, m_conv_w + l*1024*4, m_conv_b + l*1024, XC);
    gemm64_kernel<ACT_NONE><<<dim3(1,16),256,0,stream>>>(
        XC, m_xproj_w + (size_t)l*1024*64, nullptr, XDBL, 1024, 1024, 64, 64);
    gemm64_kernel<ACT_SOFTPLUS><<<dim3(16,16),256,0,stream>>>(
        XDBL, m_dt_w + (size_t)l*32*1024, m_dt_b + l*1024, DT, 32, 64, 1024, 1024);
    scan1_kernel<<<128,256,0,stream>>>(DT, XC, XDBL, m_Alog + l*16384, HEND, PPR);
    scan2_kernel<<<64,256,0,stream>>>(HEND, PPR, CIN);
    scan3_kernel<<<128,256,0,stream>>>(DT, XC, XDBL, m_Alog + l*16384, CIN, m_D + l*1024, XZ, Y);
    gemm64_kernel<ACT_NONE><<<dim3(8,16),256,0,stream>>>(
        Y, m_out_w + (size_t)l*1024*512, nullptr, TMP, 1024, 1024, 512, 512);
    ln_kernel<1><<<256,256,0,stream>>>(TMP, XM, m_ln_g + l*512, m_ln_b + l*512, XM, 512);
  }

  pool1_kernel<<<1,1024,0,stream>>>(XM, pool_w, pool_b, PW);
  pool2_kernel<<<2,256,0,stream>>>(XM, PW, HP);
  head_kernel<<<1,128,0,stream>>>(HP, h1_w, h1_b, hg1, hb1, h2_w, h2_b, hg2, hb2, h3_w, h3_b, out);
  copyx_kernel<<<2048,256,0,stream>>>(XM, out);
}

// Round 3
// 10454.066 us; speedup vs baseline: 1.3895x; 1.3895x over previous
//
#include <hip/hip_runtime.h>
#include <math.h>

// ---------------- activations ----------------
#define ACT_NONE 0
#define ACT_GELU 1
#define ACT_SOFTPLUS 2

template<int ACT>
__device__ __forceinline__ float act_apply(float x){
  if (ACT == ACT_GELU)     return 0.5f * x * (1.0f + erff(x * 0.70710678118654752f));
  if (ACT == ACT_SOFTPLUS) return fmaxf(x, 0.0f) + log1pf(expf(-fabsf(x)));
  return x;
}

// ---------------- GEMM 128x128 tile, 256 thr, 8x8/thread, Ktile=16 ----------------
// C[M,N] = act(A@W + bias [+ pos]) (+C if ACC). POS: adds pos[(row&63)*256+col] (embed only).
template<int ACT, int ACC, int POS>
__global__ __launch_bounds__(256) void gemm128_kernel(
    const float* __restrict__ A, const float* __restrict__ W,
    const float* __restrict__ bias, const float* __restrict__ pos,
    float* __restrict__ C, int K, int lda, int ldw, int ldc)
{
  __shared__ float As[16][128];
  __shared__ float Ws[16][128];
  const int tid = threadIdx.x;
  const int m0 = blockIdx.y * 128;
  const int n0 = blockIdx.x * 128;
  const int tx = tid & 15, ty = tid >> 4;
  const int ar = tid >> 2, ak = (tid & 3) * 4;
  const int wk = tid >> 5, wn = (tid & 31) * 4;

  float acc[8][8];
#pragma unroll
  for (int i = 0; i < 8; i++)
#pragma unroll
    for (int j = 0; j < 8; j++) acc[i][j] = 0.0f;

  for (int k0 = 0; k0 < K; k0 += 16) {
    float4 a0 = *(const float4*)(A + (size_t)(m0 + ar)      * lda + k0 + ak);
    float4 a1 = *(const float4*)(A + (size_t)(m0 + ar + 64) * lda + k0 + ak);
    float4 w0 = *(const float4*)(W + (size_t)(k0 + wk)     * ldw + n0 + wn);
    float4 w1 = *(const float4*)(W + (size_t)(k0 + wk + 8) * ldw + n0 + wn);
    __syncthreads();
    As[ak + 0][ar] = a0.x; As[ak + 1][ar] = a0.y; As[ak + 2][ar] = a0.z; As[ak + 3][ar] = a0.w;
    As[ak + 0][ar + 64] = a1.x; As[ak + 1][ar + 64] = a1.y; As[ak + 2][ar + 64] = a1.z; As[ak + 3][ar + 64] = a1.w;
    *(float4*)&Ws[wk][wn] = w0;
    *(float4*)&Ws[wk + 8][wn] = w1;
    __syncthreads();
#pragma unroll
    for (int k = 0; k < 16; k++) {
      float4 xa = *(float4*)&As[k][ty * 8];
      float4 xb = *(float4*)&As[k][ty * 8 + 4];
      float4 y0 = *(float4*)&Ws[k][tx * 8];
      float4 y1 = *(float4*)&Ws[k][tx * 8 + 4];
      float a8[8] = {xa.x, xa.y, xa.z, xa.w, xb.x, xb.y, xb.z, xb.w};
      float b8[8] = {y0.x, y0.y, y0.z, y0.w, y1.x, y1.y, y1.z, y1.w};
#pragma unroll
      for (int i = 0; i < 8; i++)
#pragma unroll
        for (int j = 0; j < 8; j++) acc[i][j] = fmaf(a8[i], b8[j], acc[i][j]);
    }
  }
#pragma unroll
  for (int i = 0; i < 8; i++) {
    int row = m0 + ty * 8 + i;
    float* cp = C + (size_t)row * ldc + n0 + tx * 8;
    float v[8];
#pragma unroll
    for (int j = 0; j < 8; j++) {
      float t = acc[i][j];
      int col = n0 + tx * 8 + j;
      if (bias) t += bias[col];
      if (POS)  t += pos[(row & 63) * 256 + col];
      t = act_apply<ACT>(t);
      if (ACC) t += cp[j];
      v[j] = t;
    }
    *(float4*)cp       = make_float4(v[0], v[1], v[2], v[3]);
    *(float4*)(cp + 4) = make_float4(v[4], v[5], v[6], v[7]);
  }
}

// ---------------- GEMM 64x64 tile, 256 thr, 4x4/thread ----------------
template<int ACT>
__global__ __launch_bounds__(256) void gemm64_kernel(
    const float* __restrict__ A, const float* __restrict__ W,
    const float* __restrict__ bias, float* __restrict__ C,
    int K, int lda, int ldw, int ldc)
{
  __shared__ float As[16][64];
  __shared__ float Ws[16][64];
  const int tid = threadIdx.x;
  const int m0 = blockIdx.y * 64;
  const int n0 = blockIdx.x * 64;
  const int tx = tid & 15, ty = tid >> 4;
  const int ar = tid >> 2, ak = (tid & 3) * 4;
  const int wk = tid >> 4, wn = (tid & 15) * 4;

  float acc[4][4];
#pragma unroll
  for (int i = 0; i < 4; i++)
#pragma unroll
    for (int j = 0; j < 4; j++) acc[i][j] = 0.0f;

  for (int k0 = 0; k0 < K; k0 += 16) {
    float4 a0 = *(const float4*)(A + (size_t)(m0 + ar) * lda + k0 + ak);
    float4 w0 = *(const float4*)(W + (size_t)(k0 + wk) * ldw + n0 + wn);
    __syncthreads();
    As[ak + 0][ar] = a0.x; As[ak + 1][ar] = a0.y; As[ak + 2][ar] = a0.z; As[ak + 3][ar] = a0.w;
    *(float4*)&Ws[wk][wn] = w0;
    __syncthreads();
#pragma unroll
    for (int k = 0; k < 16; k++) {
      float4 xa = *(float4*)&As[k][ty * 4];
      float4 yb = *(float4*)&Ws[k][tx * 4];
      float a4[4] = {xa.x, xa.y, xa.z, xa.w};
      float b4[4] = {yb.x, yb.y, yb.z, yb.w};
#pragma unroll
      for (int i = 0; i < 4; i++)
#pragma unroll
        for (int j = 0; j < 4; j++) acc[i][j] = fmaf(a4[i], b4[j], acc[i][j]);
    }
  }
#pragma unroll
  for (int i = 0; i < 4; i++) {
    float* cp = C + (size_t)(m0 + ty * 4 + i) * ldc + n0 + tx * 4;
    float v[4];
#pragma unroll
    for (int j = 0; j < 4; j++) {
      float t = acc[i][j];
      if (bias) t += bias[n0 + tx * 4 + j];
      v[j] = act_apply<ACT>(t);
    }
    *(float4*)cp = make_float4(v[0], v[1], v[2], v[3]);
  }
}

// ---------------- fused attention (scores + softmax + PV), one block per (n,h) ---
__global__ __launch_bounds__(64) void attn_fused_kernel(
    const float* __restrict__ QKVc, const float* __restrict__ mask,
    float* __restrict__ ATTOc, int n0)
{
  int bid = blockIdx.x;
  int nl = bid >> 3;          // chunk-local sequence
  int h = bid & 7;
  int n = n0 + nl;            // global sequence (mask)
  int tid = threadIdx.x;
  int tx = tid & 7, ty = tid >> 3;
  __shared__ float Qt[32][68];
  __shared__ float Kt[32][68];
  __shared__ float Vs[64][36];
  __shared__ float Pt[64][68];   // Pt[key][query]
  __shared__ float bs[64];
  const float* base = QKVc + (size_t)nl * (64 * 768);
#pragma unroll
  for (int i = 0; i < 32; i++) {
    int idx = tid + i * 64;
    int bar = idx >> 5, c = idx & 31;
    Qt[c][bar] = base[bar * 768 + h * 32 + c];
    Kt[c][bar] = base[bar * 768 + 256 + h * 32 + c];
    Vs[bar][c] = base[bar * 768 + 512 + h * 32 + c];
  }
  bs[tid] = (1.0f - mask[n * 64 + tid]) * -1e9f;
  __syncthreads();
  float acc[8][8] = {};
  for (int c = 0; c < 32; c++) {
    float4 ax = *(float4*)&Qt[c][ty * 8];
    float4 ay = *(float4*)&Qt[c][ty * 8 + 4];
    float4 bx = *(float4*)&Kt[c][tx * 8];
    float4 by = *(float4*)&Kt[c][tx * 8 + 4];
    float a8[8] = {ax.x, ax.y, ax.z, ax.w, ay.x, ay.y, ay.z, ay.w};
    float b8[8] = {bx.x, bx.y, bx.z, bx.w, by.x, by.y, by.z, by.w};
#pragma unroll
    for (int i = 0; i < 8; i++)
#pragma unroll
      for (int j = 0; j < 8; j++) acc[i][j] = fmaf(a8[i], b8[j], acc[i][j]);
  }
  const float scale = 0.17677669529663687f;
#pragma unroll
  for (int i = 0; i < 8; i++) {
    float s[8];
    float mx = -3.0e38f;
#pragma unroll
    for (int j = 0; j < 8; j++) { s[j] = acc[i][j] * scale + bs[tx * 8 + j]; mx = fmaxf(mx, s[j]); }
#pragma unroll
    for (int off = 1; off < 8; off <<= 1) mx = fmaxf(mx, __shfl_xor(mx, off));
    float sum = 0.0f;
#pragma unroll
    for (int j = 0; j < 8; j++) { s[j] = expf(s[j] - mx); sum += s[j]; }
#pragma unroll
    for (int off = 1; off < 8; off <<= 1) sum += __shfl_xor(sum, off);
    float inv = 1.0f / sum;
#pragma unroll
    for (int j = 0; j < 8; j++) Pt[tx * 8 + j][ty * 8 + i] = s[j] * inv;
  }
  __syncthreads();
  float o[8][4] = {};
  for (int j = 0; j < 64; j++) {
    float4 px = *(float4*)&Pt[j][ty * 8];
    float4 py = *(float4*)&Pt[j][ty * 8 + 4];
    float4 v  = *(float4*)&Vs[j][tx * 4];
    float p8[8] = {px.x, px.y, px.z, px.w, py.x, py.y, py.z, py.w};
#pragma unroll
    for (int i = 0; i < 8; i++) {
      o[i][0] = fmaf(p8[i], v.x, o[i][0]);
      o[i][1] = fmaf(p8[i], v.y, o[i][1]);
      o[i][2] = fmaf(p8[i], v.z, o[i][2]);
      o[i][3] = fmaf(p8[i], v.w, o[i][3]);
    }
  }
#pragma unroll
  for (int i = 0; i < 8; i++) {
    float* op = ATTOc + (size_t)(nl * 64 + ty * 8 + i) * 256 + h * 32 + tx * 4;
    *(float4*)op = make_float4(o[i][0], o[i][1], o[i][2], o[i][3]);
  }
}

// ---------------- LayerNorm (wave per row) ----------------
// MODE 0: o = LN(a+b)*g+beta     MODE 1: o = LN(a)*g+beta + b
template<int MODE>
__global__ __launch_bounds__(256) void ln_kernel(
    const float* __restrict__ a, const float* __restrict__ b,
    const float* __restrict__ g, const float* __restrict__ beta,
    float* __restrict__ o, int Wd)
{
  int wave = threadIdx.x >> 6;
  int lane = threadIdx.x & 63;
  int row = blockIdx.x * 4 + wave;
  int P = Wd >> 6;
  const float* ar = a + (size_t)row * Wd;
  const float* br = b + (size_t)row * Wd;
  float v[8];
  float s = 0.0f;
  for (int i = 0; i < P; i++) {
    float x = ar[lane + i * 64];
    if (MODE == 0) x += br[lane + i * 64];
    v[i] = x; s += x;
  }
#pragma unroll
  for (int off = 32; off; off >>= 1) s += __shfl_xor(s, off);
  float mean = s / Wd;
  float vs = 0.0f;
  for (int i = 0; i < P; i++) { float d = v[i] - mean; vs += d * d; }
#pragma unroll
  for (int off = 32; off; off >>= 1) vs += __shfl_xor(vs, off);
  float rstd = rsqrtf(vs / Wd + 1e-5f);
  for (int i = 0; i < P; i++) {
    int col = lane + i * 64;
    float t = (v[i] - mean) * rstd * g[col] + beta[col];
    if (MODE == 1) t += br[col];
    o[(size_t)row * Wd + col] = t;
  }
}

// ---------------- masked mean over bars (chunk-local X, global FE) ----------------
__global__ __launch_bounds__(256) void mean_kernel(
    const float* __restrict__ Xc, const float* __restrict__ mask,
    float* __restrict__ FE, int n0)
{
  int n = blockIdx.x;         // chunk-local
  int c = threadIdx.x;
  float s = 0.0f, ms = 0.0f;
  for (int bar = 0; bar < 64; bar++) {
    float mk = mask[(n0 + n) * 64 + bar];
    s = fmaf(Xc[(size_t)(n * 64 + bar) * 256 + c], mk, s);
    ms += mk;
  }
  FE[(n0 + n) * 256 + c] = s / fmaxf(ms, 1.0f);
}

// ---------------- mamba conv (4-tap causal) + silu ----------------
__global__ __launch_bounds__(256) void conv_kernel(
    const float* __restrict__ XZ, const float* __restrict__ w,
    const float* __restrict__ b, float* __restrict__ XC)
{
  int idx = blockIdx.x * 256 + threadIdx.x;
  int t = idx >> 10, c = idx & 1023;
  float acc = b[c];
  const float* wc = w + c * 4;
#pragma unroll
  for (int k = 0; k < 4; k++) {
    int tt = t + k - 3;
    if (tt >= 0) acc = fmaf(XZ[(size_t)tt * 2048 + c], wc[k], acc);
  }
  XC[idx] = acc / (1.0f + expf(-acc));
}

// ---------------- chunked scan (32 chunks x 32 steps) ----------------
#define NCH 32
#define CLEN 32

__global__ __launch_bounds__(256) void scan1_kernel(
    const float* __restrict__ DT, const float* __restrict__ XC,
    const float* __restrict__ XDBL, const float* __restrict__ Alog,
    float* __restrict__ HEND, float* __restrict__ PPR)
{
  int j = blockIdx.x >> 2;
  int c = (blockIdx.x & 3) * 256 + threadIdx.x;
  int t0 = j * CLEN;
  __shared__ float Bs[CLEN][16];
  for (int i = threadIdx.x; i < CLEN * 16; i += 256) {
    int r = i >> 4, s = i & 15;
    Bs[r][s] = XDBL[(t0 + r) * 64 + 32 + s];
  }
  float A[16], h[16], Pp[16];
#pragma unroll
  for (int s = 0; s < 16; s++) {
    A[s] = -expf(Alog[c * 16 + s]);
    h[s] = 0.0f; Pp[s] = 1.0f;
  }
  __syncthreads();
  for (int tt = 0; tt < CLEN; tt++) {
    int t = t0 + tt;
    float dtv = DT[(size_t)t * 1024 + c];
    float u = dtv * XC[(size_t)t * 1024 + c];
#pragma unroll
    for (int s = 0; s < 16; s++) {
      float e = expf(dtv * A[s]);
      h[s] = fmaf(h[s], e, u * Bs[tt][s]);
      Pp[s] *= e;
    }
  }
#pragma unroll
  for (int s = 0; s < 16; s++) {
    HEND[(size_t)(j * 1024 + c) * 16 + s] = h[s];
    PPR [(size_t)(j * 1024 + c) * 16 + s] = Pp[s];
  }
}

__global__ __launch_bounds__(256) void scan2_kernel(
    const float* __restrict__ HEND, const float* __restrict__ PPR, float* __restrict__ CIN)
{
  int id = blockIdx.x * 256 + threadIdx.x;
  float carry = 0.0f;
  for (int j = 0; j < NCH; j++) {
    CIN[j * 16384 + id] = carry;
    carry = fmaf(PPR[j * 16384 + id], carry, HEND[j * 16384 + id]);
  }
}

__global__ __launch_bounds__(256) void scan3_kernel(
    const float* __restrict__ DT, const float* __restrict__ XC,
    const float* __restrict__ XDBL, const float* __restrict__ Alog,
    const float* __restrict__ CIN, const float* __restrict__ mD,
    const float* __restrict__ XZ, float* __restrict__ Y)
{
  int j = blockIdx.x >> 2;
  int c = (blockIdx.x & 3) * 256 + threadIdx.x;
  int t0 = j * CLEN;
  __shared__ float Bs[CLEN][16], Cs[CLEN][16];
  for (int i = threadIdx.x; i < CLEN * 16; i += 256) {
    int r = i >> 4, s = i & 15;
    Bs[r][s] = XDBL[(t0 + r) * 64 + 32 + s];
    Cs[r][s] = XDBL[(t0 + r) * 64 + 48 + s];
  }
  float A[16], h[16];
#pragma unroll
  for (int s = 0; s < 16; s++) {
    A[s] = -expf(Alog[c * 16 + s]);
    h[s] = CIN[(size_t)(j * 1024 + c) * 16 + s];
  }
  float dval = mD[c];
  __syncthreads();
  for (int tt = 0; tt < CLEN; tt++) {
    int t = t0 + tt;
    float dtv = DT[(size_t)t * 1024 + c];
    float xcv = XC[(size_t)t * 1024 + c];
    float u = dtv * xcv;
    float y = 0.0f;
#pragma unroll
    for (int s = 0; s < 16; s++) {
      float e = expf(dtv * A[s]);
      h[s] = fmaf(h[s], e, u * Bs[tt][s]);
      y = fmaf(h[s], Cs[tt][s], y);
    }
    float z = XZ[(size_t)t * 2048 + 1024 + c];
    float sz = z / (1.0f + expf(-z));
    Y[(size_t)t * 1024 + c] = (y + dval * xcv) * sz;
  }
}

// ---------------- pooling + head ----------------
__global__ __launch_bounds__(1024) void pool1_kernel(
    const float* __restrict__ XM, const float* __restrict__ pw,
    const float* __restrict__ pb, float* __restrict__ PW)
{
  int t = threadIdx.x;
  float s = pb[0];
  for (int i = 0; i < 512; i++) s = fmaf(XM[(size_t)t * 512 + i], pw[i], s);
  __shared__ float red[1024];
  red[t] = s;
  __syncthreads();
  for (int off = 512; off > 0; off >>= 1) {
    if (t < off) red[t] = fmaxf(red[t], red[t + off]);
    __syncthreads();
  }
  float mx = red[0];
  __syncthreads();
  float e = expf(s - mx);
  red[t] = e;
  __syncthreads();
  for (int off = 512; off > 0; off >>= 1) {
    if (t < off) red[t] = red[t] + red[t + off];
    __syncthreads();
  }
  PW[t] = e / red[0];
}

__global__ __launch_bounds__(256) void pool2_kernel(
    const float* __restrict__ XM, const float* __restrict__ PW, float* __restrict__ HP)
{
  int hcol = blockIdx.x * 256 + threadIdx.x;
  float s = 0.0f;
  for (int tn = 0; tn < 1024; tn++) s = fmaf(PW[tn], XM[(size_t)tn * 512 + hcol], s);
  HP[hcol] = s;
}

__device__ __forceinline__ float blk_reduce_sum_128(float v, float* red){
  int t = threadIdx.x;
#pragma unroll
  for (int off = 32; off; off >>= 1) v += __shfl_xor(v, off);
  __syncthreads();
  if ((t & 63) == 0) red[t >> 6] = v;
  __syncthreads();
  return red[0] + red[1];
}

__global__ __launch_bounds__(128) void head_kernel(
    const float* __restrict__ HP, const float* __restrict__ h1w, const float* __restrict__ h1b,
    const float* __restrict__ g1, const float* __restrict__ be1,
    const float* __restrict__ h2w, const float* __restrict__ h2b,
    const float* __restrict__ g2, const float* __restrict__ be2,
    const float* __restrict__ h3w, const float* __restrict__ h3b,
    float* __restrict__ out)
{
  __shared__ float t1[128];
  __shared__ float red[2];
  int i = threadIdx.x;
  float s = h1b[i];
  for (int k = 0; k < 512; k++) s = fmaf(HP[k], h1w[k * 128 + i], s);
  float mean = blk_reduce_sum_128(s, red) * (1.0f / 128.0f);
  float d = s - mean;
  float var = blk_reduce_sum_128(d * d, red) * (1.0f / 128.0f);
  float x1 = d * rsqrtf(var + 1e-5f) * g1[i] + be1[i];
  x1 = 0.5f * x1 * (1.0f + erff(x1 * 0.70710678118654752f));
  t1[i] = x1;
  __syncthreads();
  s = h2b[i];
  for (int k = 0; k < 128; k++) s = fmaf(t1[k], h2w[k * 128 + i], s);
  mean = blk_reduce_sum_128(s, red) * (1.0f / 128.0f);
  d = s - mean;
  var = blk_reduce_sum_128(d * d, red) * (1.0f / 128.0f);
  float x2 = d * rsqrtf(var + 1e-5f) * g2[i] + be2[i];
  x2 = 0.5f * x2 * (1.0f + erff(x2 * 0.70710678118654752f));
  float tot = blk_reduce_sum_128(x2 * h3w[i], red);
  if (i == 0) out[0] = tot + h3b[0];
}

__global__ __launch_bounds__(256) void copyx_kernel(const float* __restrict__ XM, float* __restrict__ out){
  int i = blockIdx.x * 256 + threadIdx.x;
  out[1 + i] = XM[i];
}

// ---------------- launch ----------------
extern "C" void kernel_launch(void* const* d_in, const int* in_sizes, int n_in,
                              void* d_out, int out_size, void* d_ws, size_t ws_size,
                              hipStream_t stream)
{
  const float* frames   = (const float*)d_in[0];
  const float* fmask    = (const float*)d_in[1];
  const float* in_w     = (const float*)d_in[2];
  const float* in_b     = (const float*)d_in[3];
  const float* pos_emb  = (const float*)d_in[4];
  const float* qkv_w    = (const float*)d_in[5];
  const float* qkv_b    = (const float*)d_in[6];
  const float* ao_w     = (const float*)d_in[7];
  const float* ao_b     = (const float*)d_in[8];
  const float* ln1_g    = (const float*)d_in[9];
  const float* ln1_b    = (const float*)d_in[10];
  const float* ffn_w1   = (const float*)d_in[11];
  const float* ffn_b1   = (const float*)d_in[12];
  const float* ffn_w2   = (const float*)d_in[13];
  const float* ffn_b2   = (const float*)d_in[14];
  const float* ln2_g    = (const float*)d_in[15];
  const float* ln2_b    = (const float*)d_in[16];
  const float* proj_w   = (const float*)d_in[17];
  const float* proj_b   = (const float*)d_in[18];
  const float* m_in_w   = (const float*)d_in[19];
  const float* m_conv_w = (const float*)d_in[20];
  const float* m_conv_b = (const float*)d_in[21];
  const float* m_xproj_w= (const float*)d_in[22];
  const float* m_dt_w   = (const float*)d_in[23];
  const float* m_dt_b   = (const float*)d_in[24];
  const float* m_Alog   = (const float*)d_in[25];
  const float* m_D      = (const float*)d_in[26];
  const float* m_out_w  = (const float*)d_in[27];
  const float* m_ln_g   = (const float*)d_in[28];
  const float* m_ln_b   = (const float*)d_in[29];
  const float* pool_w   = (const float*)d_in[30];
  const float* pool_b   = (const float*)d_in[31];
  const float* h1_w     = (const float*)d_in[32];
  const float* h1_b     = (const float*)d_in[33];
  const float* hg1      = (const float*)d_in[34];
  const float* hb1      = (const float*)d_in[35];
  const float* h2_w     = (const float*)d_in[36];
  const float* h2_b     = (const float*)d_in[37];
  const float* hg2      = (const float*)d_in[38];
  const float* hb2      = (const float*)d_in[39];
  const float* h3_w     = (const float*)d_in[40];
  const float* h3_b     = (const float*)d_in[41];
  float* out = (float*)d_out;

  // ---- workspace: chunk-through-layers layout, ~26.1M floats = 104 MB ----
  // 4 chunks of 256 sequences (16384 rows of 256)
  float* ws = (float*)d_ws;
  float* Xc = ws;                  //  4,194,304  chunk encoder state (16384 x 256)
  float* QF = Xc + 4194304;        // 12,582,912  QKV chunk (16384x768) / FFN tmp (16384x512) / mamba scratch
  float* AT = QF + 12582912;       //  4,194,304  attn out chunk
  float* RC = AT + 4194304;        //  4,194,304  residual chunk
  float* FE = RC + 4194304;        //    262,144  frame_emb (1024x256)
  float* XM = FE + 262144;         //    524,288  mamba state (1024x512)
  float* PW = XM + 524288;         //      2,048
  float* HP = PW + 2048;           //      1,024

  // mamba aliases inside QF (7,405,568 floats needed; QF holds 12.58M)
  float* XZ   = QF;                // 2,097,152  (1024x2048)
  float* XC   = QF + 2097152;      // 1,048,576
  float* DT   = QF + 3145728;      // 1,048,576
  float* XDBL = QF + 4194304;      //    65,536
  float* Y    = QF + 4259840;      // 1,048,576
  float* TMP  = QF + 5308416;      //   524,288
  float* HEND = QF + 5832704;      //   524,288
  float* PPR  = QF + 6356992;      //   524,288
  float* CIN  = QF + 6881280;      //   524,288

  // ---- encoder: 4 chunks of 256 sequences, all 4 layers per chunk ----
  for (int ch = 0; ch < 4; ch++) {
    int n0 = ch * 256;
    const float* fch = frames + (size_t)n0 * 64 * 32;
    // embed + pos (fused): grid 2x128 = 256 blocks
    gemm128_kernel<ACT_NONE,0,1><<<dim3(2,128),256,0,stream>>>(
        fch, in_w, in_b, pos_emb, Xc, 32, 32, 256, 256);
    for (int l = 0; l < 4; l++) {
      // QKV: grid 6x128 = 768
      gemm128_kernel<ACT_NONE,0,0><<<dim3(6,128),256,0,stream>>>(
          Xc, qkv_w + (size_t)l*256*768, qkv_b + l*768, nullptr, QF, 256, 256, 768, 768);
      // fused attention: 2048 blocks
      attn_fused_kernel<<<2048,64,0,stream>>>(QF, fmask, AT, n0);
      // out-proj: grid 2x128 = 256
      gemm128_kernel<ACT_NONE,0,0><<<dim3(2,128),256,0,stream>>>(
          AT, ao_w + (size_t)l*256*256, ao_b + l*256, nullptr, RC, 256, 256, 256, 256);
      ln_kernel<0><<<4096,256,0,stream>>>(Xc, RC, ln1_g + l*256, ln1_b + l*256, Xc, 256);
      // FFN: two column halves of 512, tmp in QF (free after attention)
      for (int half = 0; half < 2; half++) {
        gemm128_kernel<ACT_GELU,0,0><<<dim3(4,128),256,0,stream>>>(
            Xc, ffn_w1 + (size_t)l*256*1024 + half*512, ffn_b1 + l*1024 + half*512, nullptr,
            QF, 256, 256, 1024, 512);
        if (half == 0)
          gemm128_kernel<ACT_NONE,0,0><<<dim3(2,128),256,0,stream>>>(
              QF, ffn_w2 + (size_t)l*1024*256, ffn_b2 + l*256, nullptr, RC, 512, 512, 256, 256);
        else
          gemm128_kernel<ACT_NONE,1,0><<<dim3(2,128),256,0,stream>>>(
              QF, ffn_w2 + (size_t)l*1024*256 + 512*256, nullptr, nullptr, RC, 512, 512, 256, 256);
      }
      ln_kernel<0><<<4096,256,0,stream>>>(Xc, RC, ln2_g + l*256, ln2_b + l*256, Xc, 256);
    }
    // masked mean for this chunk's sequences
    mean_kernel<<<256,256,0,stream>>>(Xc, fmask, FE, n0);
  }

  gemm64_kernel<ACT_NONE><<<dim3(8,16),256,0,stream>>>(FE, proj_w, proj_b, XM, 256, 256, 512, 512);

  for (int l = 0; l < 8; l++) {
    gemm64_kernel<ACT_NONE><<<dim3(32,16),256,0,stream>>>(
        XM, m_in_w + (size_t)l*512*2048, nullptr, XZ, 512, 512, 2048, 2048);
    conv_kernel<<<4096,256,0,stream>>>(XZ, m_conv_w + l*1024*4, m_conv_b + l*1024, XC);
    gemm64_kernel<ACT_NONE><<<dim3(1,16),256,0,stream>>>(
        XC, m_xproj_w + (size_t)l*1024*64, nullptr, XDBL, 1024, 1024, 64, 64);
    gemm64_kernel<ACT_SOFTPLUS><<<dim3(16,16),256,0,stream>>>(
        XDBL, m_dt_w + (size_t)l*32*1024, m_dt_b + l*1024, DT, 32, 64, 1024, 1024);
    scan1_kernel<<<128,256,0,stream>>>(DT, XC, XDBL, m_Alog + l*16384, HEND, PPR);
    scan2_kernel<<<64,256,0,stream>>>(HEND, PPR, CIN);
    scan3_kernel<<<128,256,0,stream>>>(DT, XC, XDBL, m_Alog + l*16384, CIN, m_D + l*1024, XZ, Y);
    gemm64_kernel<ACT_NONE><<<dim3(8,16),256,0,stream>>>(
        Y, m_out_w + (size_t)l*1024*512, nullptr, TMP, 1024, 1024, 512, 512);
    ln_kernel<1><<<256,256,0,stream>>>(TMP, XM, m_ln_g + l*512, m_ln_b + l*512, XM, 512);
  }

  pool1_kernel<<<1,1024,0,stream>>>(XM, pool_w, pool_b, PW);
  pool2_kernel<<<2,256,0,stream>>>(XM, PW, HP);
  head_kernel<<<1,128,0,stream>>>(HP, h1_w, h1_b, hg1, hb1, h2_w, h2_b, hg2, hb2, h3_w, h3_b, out);
  copyx_kernel<<<2048,256,0,stream>>>(XM, out);
}

// Round 4
// 8910.414 us; speedup vs baseline: 1.6302x; 1.1732x over previous
//
#include <hip/hip_runtime.h>
#include <math.h>

// ---------------- activations ----------------
#define ACT_NONE 0
#define ACT_GELU 1
#define ACT_SOFTPLUS 2

template<int ACT>
__device__ __forceinline__ float act_apply(float x){
  if (ACT == ACT_GELU)     return 0.5f * x * (1.0f + erff(x * 0.70710678118654752f));
  if (ACT == ACT_SOFTPLUS) return fmaxf(x, 0.0f) + log1pf(expf(-fabsf(x)));
  return x;
}

// ---------------- bf16 split helpers ----------------
__device__ __forceinline__ unsigned short f2bf(float x){
  unsigned u = __float_as_uint(x);
  u = u + 0x7FFFu + ((u >> 16) & 1u);
  return (unsigned short)(u >> 16);
}
__device__ __forceinline__ float bf2f(unsigned short b){
  return __uint_as_float(((unsigned)b) << 16);
}
__device__ __forceinline__ void bfsplit(float x, unsigned short &hi, unsigned short &lo){
  hi = f2bf(x);
  lo = f2bf(x - bf2f(hi));
}

typedef __attribute__((ext_vector_type(8))) short v8s;
typedef __attribute__((ext_vector_type(4))) float v4f;

// ---------------- bf16x2 MFMA GEMM: 128x128 tile, 256 thr (4 waves) ------------
// A stored [M][K] bf16 hi/lo; B stored TRANSPOSED [N][K] bf16 hi/lo.
// OUT: 0 = fp32 store (+bias), 1 = fp32 accumulate into C, 2 = bf16-split store.
template<int ACT, int OUT>
__global__ __launch_bounds__(256) void gemm_bf16x2_kernel(
    const unsigned short* __restrict__ Ahi, const unsigned short* __restrict__ Alo,
    const unsigned short* __restrict__ Bhi, const unsigned short* __restrict__ Blo,
    const float* __restrict__ bias, float* __restrict__ C,
    unsigned short* __restrict__ Chi, unsigned short* __restrict__ Clo,
    int K, int lda, int ldb, int ldc)
{
  __shared__ unsigned short As[2][128][48];   // hi/lo, row pad 48 (96B, 16B-aligned)
  __shared__ unsigned short Bs[2][128][48];
  const int tid = threadIdx.x;
  const int m0 = blockIdx.y * 128;
  const int n0 = blockIdx.x * 128;
  const int w = tid >> 6, lane = tid & 63;
  const int wm = (w & 1) * 64, wn = (w >> 1) * 64;
  const int fm = lane & 15, fq = lane >> 4;
  const int r = tid >> 1, h = tid & 1;      // staging: row, k-half

  v4f acc[4][4];
#pragma unroll
  for (int i = 0; i < 4; i++)
#pragma unroll
    for (int j = 0; j < 4; j++) acc[i][j] = (v4f){0.f, 0.f, 0.f, 0.f};

  for (int k0 = 0; k0 < K; k0 += 32) {
    const uint4* gah = (const uint4*)(Ahi + (size_t)(m0 + r) * lda + k0 + h * 16);
    const uint4* gal = (const uint4*)(Alo + (size_t)(m0 + r) * lda + k0 + h * 16);
    const uint4* gbh = (const uint4*)(Bhi + (size_t)(n0 + r) * ldb + k0 + h * 16);
    const uint4* gbl = (const uint4*)(Blo + (size_t)(n0 + r) * ldb + k0 + h * 16);
    uint4 ah0 = gah[0], ah1 = gah[1];
    uint4 al0 = gal[0], al1 = gal[1];
    uint4 bh0 = gbh[0], bh1 = gbh[1];
    uint4 bl0 = gbl[0], bl1 = gbl[1];
    __syncthreads();
    *(uint4*)&As[0][r][h * 16]     = ah0;
    *(uint4*)&As[0][r][h * 16 + 8] = ah1;
    *(uint4*)&As[1][r][h * 16]     = al0;
    *(uint4*)&As[1][r][h * 16 + 8] = al1;
    *(uint4*)&Bs[0][r][h * 16]     = bh0;
    *(uint4*)&Bs[0][r][h * 16 + 8] = bh1;
    *(uint4*)&Bs[1][r][h * 16]     = bl0;
    *(uint4*)&Bs[1][r][h * 16 + 8] = bl1;
    __syncthreads();

    v8s ah[4], al[4];
#pragma unroll
    for (int i = 0; i < 4; i++) {
      ah[i] = *(const v8s*)&As[0][wm + i * 16 + fm][fq * 8];
      al[i] = *(const v8s*)&As[1][wm + i * 16 + fm][fq * 8];
    }
#pragma unroll
    for (int j = 0; j < 4; j++) {
      v8s bh = *(const v8s*)&Bs[0][wn + j * 16 + fm][fq * 8];
      v8s bl = *(const v8s*)&Bs[1][wn + j * 16 + fm][fq * 8];
#pragma unroll
      for (int i = 0; i < 4; i++) {
        acc[i][j] = __builtin_amdgcn_mfma_f32_16x16x32_bf16(ah[i], bh, acc[i][j], 0, 0, 0);
        acc[i][j] = __builtin_amdgcn_mfma_f32_16x16x32_bf16(ah[i], bl, acc[i][j], 0, 0, 0);
        acc[i][j] = __builtin_amdgcn_mfma_f32_16x16x32_bf16(al[i], bh, acc[i][j], 0, 0, 0);
      }
    }
  }

  // C/D layout (16x16): col = lane&15, row = (lane>>4)*4 + reg
#pragma unroll
  for (int i = 0; i < 4; i++)
#pragma unroll
    for (int j = 0; j < 4; j++) {
      int col = n0 + wn + j * 16 + fm;
      float bv = bias ? bias[col] : 0.0f;
#pragma unroll
      for (int reg = 0; reg < 4; reg++) {
        int row = m0 + wm + i * 16 + fq * 4 + reg;
        float v = acc[i][j][reg] + bv;
        v = act_apply<ACT>(v);
        size_t idx = (size_t)row * ldc + col;
        if (OUT == 0) C[idx] = v;
        else if (OUT == 1) C[idx] += v;
        else { unsigned short hi, lo; bfsplit(v, hi, lo); Chi[idx] = hi; Clo[idx] = lo; }
      }
    }
}

// ---------------- weight transpose + split: W[K][N] fp32 -> Wt[N][K] bf16 hi/lo --
__global__ __launch_bounds__(256) void wsplit_kernel(
    const float* __restrict__ W, unsigned short* __restrict__ Whi,
    unsigned short* __restrict__ Wlo, int K, int N)
{
  __shared__ float tile[32][33];
  int k0 = blockIdx.y * 32, n0 = blockIdx.x * 32;
  int t = threadIdx.x;
  int tn = t & 31, tk8 = t >> 5;
#pragma unroll
  for (int i = 0; i < 4; i++) {
    int k = tk8 + i * 8;
    tile[k][tn] = W[(size_t)(k0 + k) * N + n0 + tn];
  }
  __syncthreads();
  int tk = t & 31, tn8 = t >> 5;
#pragma unroll
  for (int i = 0; i < 4; i++) {
    int n = tn8 + i * 8;
    float v = tile[tk][n];
    unsigned short hi, lo; bfsplit(v, hi, lo);
    size_t idx = (size_t)(n0 + n) * K + k0 + tk;
    Whi[idx] = hi; Wlo[idx] = lo;
  }
}

// ---------------- GEMM 128x128 fp32 (embed), POS adds pos-emb, SPLIT writes hi/lo
template<int ACT, int ACC, int POS, int SPLIT>
__global__ __launch_bounds__(256) void gemm128_kernel(
    const float* __restrict__ A, const float* __restrict__ W,
    const float* __restrict__ bias, const float* __restrict__ pos,
    float* __restrict__ C, unsigned short* __restrict__ Chi, unsigned short* __restrict__ Clo,
    int K, int lda, int ldw, int ldc)
{
  __shared__ float As[16][128];
  __shared__ float Ws[16][128];
  const int tid = threadIdx.x;
  const int m0 = blockIdx.y * 128;
  const int n0 = blockIdx.x * 128;
  const int tx = tid & 15, ty = tid >> 4;
  const int ar = tid >> 2, ak = (tid & 3) * 4;
  const int wk = tid >> 5, wn = (tid & 31) * 4;

  float acc[8][8];
#pragma unroll
  for (int i = 0; i < 8; i++)
#pragma unroll
    for (int j = 0; j < 8; j++) acc[i][j] = 0.0f;

  for (int k0 = 0; k0 < K; k0 += 16) {
    float4 a0 = *(const float4*)(A + (size_t)(m0 + ar)      * lda + k0 + ak);
    float4 a1 = *(const float4*)(A + (size_t)(m0 + ar + 64) * lda + k0 + ak);
    float4 w0 = *(const float4*)(W + (size_t)(k0 + wk)     * ldw + n0 + wn);
    float4 w1 = *(const float4*)(W + (size_t)(k0 + wk + 8) * ldw + n0 + wn);
    __syncthreads();
    As[ak + 0][ar] = a0.x; As[ak + 1][ar] = a0.y; As[ak + 2][ar] = a0.z; As[ak + 3][ar] = a0.w;
    As[ak + 0][ar + 64] = a1.x; As[ak + 1][ar + 64] = a1.y; As[ak + 2][ar + 64] = a1.z; As[ak + 3][ar + 64] = a1.w;
    *(float4*)&Ws[wk][wn] = w0;
    *(float4*)&Ws[wk + 8][wn] = w1;
    __syncthreads();
#pragma unroll
    for (int k = 0; k < 16; k++) {
      float4 xa = *(float4*)&As[k][ty * 8];
      float4 xb = *(float4*)&As[k][ty * 8 + 4];
      float4 y0 = *(float4*)&Ws[k][tx * 8];
      float4 y1 = *(float4*)&Ws[k][tx * 8 + 4];
      float a8[8] = {xa.x, xa.y, xa.z, xa.w, xb.x, xb.y, xb.z, xb.w};
      float b8[8] = {y0.x, y0.y, y0.z, y0.w, y1.x, y1.y, y1.z, y1.w};
#pragma unroll
      for (int i = 0; i < 8; i++)
#pragma unroll
        for (int j = 0; j < 8; j++) acc[i][j] = fmaf(a8[i], b8[j], acc[i][j]);
    }
  }
#pragma unroll
  for (int i = 0; i < 8; i++) {
    int row = m0 + ty * 8 + i;
    float* cp = C + (size_t)row * ldc + n0 + tx * 8;
    float v[8];
#pragma unroll
    for (int j = 0; j < 8; j++) {
      float t = acc[i][j];
      int col = n0 + tx * 8 + j;
      if (bias) t += bias[col];
      if (POS)  t += pos[(row & 63) * 256 + col];
      t = act_apply<ACT>(t);
      if (ACC) t += cp[j];
      v[j] = t;
      if (SPLIT) {
        unsigned short hi, lo; bfsplit(t, hi, lo);
        size_t idx = (size_t)row * ldc + col;
        Chi[idx] = hi; Clo[idx] = lo;
      }
    }
    *(float4*)cp       = make_float4(v[0], v[1], v[2], v[3]);
    *(float4*)(cp + 4) = make_float4(v[4], v[5], v[6], v[7]);
  }
}

// ---------------- GEMM 64x64 tile fp32 (mamba) ----------------
template<int ACT>
__global__ __launch_bounds__(256) void gemm64_kernel(
    const float* __restrict__ A, const float* __restrict__ W,
    const float* __restrict__ bias, float* __restrict__ C,
    int K, int lda, int ldw, int ldc)
{
  __shared__ float As[16][64];
  __shared__ float Ws[16][64];
  const int tid = threadIdx.x;
  const int m0 = blockIdx.y * 64;
  const int n0 = blockIdx.x * 64;
  const int tx = tid & 15, ty = tid >> 4;
  const int ar = tid >> 2, ak = (tid & 3) * 4;
  const int wk = tid >> 4, wn = (tid & 15) * 4;

  float acc[4][4];
#pragma unroll
  for (int i = 0; i < 4; i++)
#pragma unroll
    for (int j = 0; j < 4; j++) acc[i][j] = 0.0f;

  for (int k0 = 0; k0 < K; k0 += 16) {
    float4 a0 = *(const float4*)(A + (size_t)(m0 + ar) * lda + k0 + ak);
    float4 w0 = *(const float4*)(W + (size_t)(k0 + wk) * ldw + n0 + wn);
    __syncthreads();
    As[ak + 0][ar] = a0.x; As[ak + 1][ar] = a0.y; As[ak + 2][ar] = a0.z; As[ak + 3][ar] = a0.w;
    *(float4*)&Ws[wk][wn] = w0;
    __syncthreads();
#pragma unroll
    for (int k = 0; k < 16; k++) {
      float4 xa = *(float4*)&As[k][ty * 4];
      float4 yb = *(float4*)&Ws[k][tx * 4];
      float a4[4] = {xa.x, xa.y, xa.z, xa.w};
      float b4[4] = {yb.x, yb.y, yb.z, yb.w};
#pragma unroll
      for (int i = 0; i < 4; i++)
#pragma unroll
        for (int j = 0; j < 4; j++) acc[i][j] = fmaf(a4[i], b4[j], acc[i][j]);
    }
  }
#pragma unroll
  for (int i = 0; i < 4; i++) {
    float* cp = C + (size_t)(m0 + ty * 4 + i) * ldc + n0 + tx * 4;
    float v[4];
#pragma unroll
    for (int j = 0; j < 4; j++) {
      float t = acc[i][j];
      if (bias) t += bias[n0 + tx * 4 + j];
      v[j] = act_apply<ACT>(t);
    }
    *(float4*)cp = make_float4(v[0], v[1], v[2], v[3]);
  }
}

// ---------------- fused attention; epilogue writes bf16-split AT ----------------
__global__ __launch_bounds__(64) void attn_fused_kernel(
    const float* __restrict__ QKVc, const float* __restrict__ mask,
    unsigned short* __restrict__ AThi, unsigned short* __restrict__ ATlo, int n0)
{
  int bid = blockIdx.x;
  int nl = bid >> 3;
  int h = bid & 7;
  int n = n0 + nl;
  int tid = threadIdx.x;
  int tx = tid & 7, ty = tid >> 3;
  __shared__ float Qt[32][68];
  __shared__ float Kt[32][68];
  __shared__ float Vs[64][36];
  __shared__ float Pt[64][68];
  __shared__ float bs[64];
  const float* base = QKVc + (size_t)nl * (64 * 768);
#pragma unroll
  for (int i = 0; i < 32; i++) {
    int idx = tid + i * 64;
    int bar = idx >> 5, c = idx & 31;
    Qt[c][bar] = base[bar * 768 + h * 32 + c];
    Kt[c][bar] = base[bar * 768 + 256 + h * 32 + c];
    Vs[bar][c] = base[bar * 768 + 512 + h * 32 + c];
  }
  bs[tid] = (1.0f - mask[n * 64 + tid]) * -1e9f;
  __syncthreads();
  float acc[8][8] = {};
  for (int c = 0; c < 32; c++) {
    float4 ax = *(float4*)&Qt[c][ty * 8];
    float4 ay = *(float4*)&Qt[c][ty * 8 + 4];
    float4 bx = *(float4*)&Kt[c][tx * 8];
    float4 by = *(float4*)&Kt[c][tx * 8 + 4];
    float a8[8] = {ax.x, ax.y, ax.z, ax.w, ay.x, ay.y, ay.z, ay.w};
    float b8[8] = {bx.x, bx.y, bx.z, bx.w, by.x, by.y, by.z, by.w};
#pragma unroll
    for (int i = 0; i < 8; i++)
#pragma unroll
      for (int j = 0; j < 8; j++) acc[i][j] = fmaf(a8[i], b8[j], acc[i][j]);
  }
  const float scale = 0.17677669529663687f;
#pragma unroll
  for (int i = 0; i < 8; i++) {
    float s[8];
    float mx = -3.0e38f;
#pragma unroll
    for (int j = 0; j < 8; j++) { s[j] = acc[i][j] * scale + bs[tx * 8 + j]; mx = fmaxf(mx, s[j]); }
#pragma unroll
    for (int off = 1; off < 8; off <<= 1) mx = fmaxf(mx, __shfl_xor(mx, off));
    float sum = 0.0f;
#pragma unroll
    for (int j = 0; j < 8; j++) { s[j] = expf(s[j] - mx); sum += s[j]; }
#pragma unroll
    for (int off = 1; off < 8; off <<= 1) sum += __shfl_xor(sum, off);
    float inv = 1.0f / sum;
#pragma unroll
    for (int j = 0; j < 8; j++) Pt[tx * 8 + j][ty * 8 + i] = s[j] * inv;
  }
  __syncthreads();
  float o[8][4] = {};
  for (int j = 0; j < 64; j++) {
    float4 px = *(float4*)&Pt[j][ty * 8];
    float4 py = *(float4*)&Pt[j][ty * 8 + 4];
    float4 v  = *(float4*)&Vs[j][tx * 4];
    float p8[8] = {px.x, px.y, px.z, px.w, py.x, py.y, py.z, py.w};
#pragma unroll
    for (int i = 0; i < 8; i++) {
      o[i][0] = fmaf(p8[i], v.x, o[i][0]);
      o[i][1] = fmaf(p8[i], v.y, o[i][1]);
      o[i][2] = fmaf(p8[i], v.z, o[i][2]);
      o[i][3] = fmaf(p8[i], v.w, o[i][3]);
    }
  }
#pragma unroll
  for (int i = 0; i < 8; i++) {
    size_t base_o = (size_t)(nl * 64 + ty * 8 + i) * 256 + h * 32 + tx * 4;
#pragma unroll
    for (int c = 0; c < 4; c++) {
      unsigned short hi, lo; bfsplit(o[i][c], hi, lo);
      AThi[base_o + c] = hi; ATlo[base_o + c] = lo;
    }
  }
}

// ---------------- LayerNorm (wave per row); SPLIT also writes bf16 hi/lo --------
// MODE 0: o = LN(a+b)*g+beta     MODE 1: o = LN(a)*g+beta + b
template<int MODE, int SPLIT>
__global__ __launch_bounds__(256) void ln_kernel(
    const float* __restrict__ a, const float* __restrict__ b,
    const float* __restrict__ g, const float* __restrict__ beta,
    float* __restrict__ o, unsigned short* __restrict__ ohi, unsigned short* __restrict__ olo,
    int Wd)
{
  int wave = threadIdx.x >> 6;
  int lane = threadIdx.x & 63;
  int row = blockIdx.x * 4 + wave;
  int P = Wd >> 6;
  const float* ar = a + (size_t)row * Wd;
  const float* br = b + (size_t)row * Wd;
  float v[8];
  float s = 0.0f;
  for (int i = 0; i < P; i++) {
    float x = ar[lane + i * 64];
    if (MODE == 0) x += br[lane + i * 64];
    v[i] = x; s += x;
  }
#pragma unroll
  for (int off = 32; off; off >>= 1) s += __shfl_xor(s, off);
  float mean = s / Wd;
  float vs = 0.0f;
  for (int i = 0; i < P; i++) { float d = v[i] - mean; vs += d * d; }
#pragma unroll
  for (int off = 32; off; off >>= 1) vs += __shfl_xor(vs, off);
  float rstd = rsqrtf(vs / Wd + 1e-5f);
  for (int i = 0; i < P; i++) {
    int col = lane + i * 64;
    float t = (v[i] - mean) * rstd * g[col] + beta[col];
    if (MODE == 1) t += br[col];
    size_t idx = (size_t)row * Wd + col;
    o[idx] = t;
    if (SPLIT) { unsigned short hi, lo; bfsplit(t, hi, lo); ohi[idx] = hi; olo[idx] = lo; }
  }
}

// ---------------- masked mean over bars ----------------
__global__ __launch_bounds__(256) void mean_kernel(
    const float* __restrict__ Xc, const float* __restrict__ mask,
    float* __restrict__ FE, int n0)
{
  int n = blockIdx.x;
  int c = threadIdx.x;
  float s = 0.0f, ms = 0.0f;
  for (int bar = 0; bar < 64; bar++) {
    float mk = mask[(n0 + n) * 64 + bar];
    s = fmaf(Xc[(size_t)(n * 64 + bar) * 256 + c], mk, s);
    ms += mk;
  }
  FE[(n0 + n) * 256 + c] = s / fmaxf(ms, 1.0f);
}

// ---------------- mamba conv (4-tap causal) + silu ----------------
__global__ __launch_bounds__(256) void conv_kernel(
    const float* __restrict__ XZ, const float* __restrict__ w,
    const float* __restrict__ b, float* __restrict__ XC)
{
  int idx = blockIdx.x * 256 + threadIdx.x;
  int t = idx >> 10, c = idx & 1023;
  float acc = b[c];
  const float* wc = w + c * 4;
#pragma unroll
  for (int k = 0; k < 4; k++) {
    int tt = t + k - 3;
    if (tt >= 0) acc = fmaf(XZ[(size_t)tt * 2048 + c], wc[k], acc);
  }
  XC[idx] = acc / (1.0f + expf(-acc));
}

// ---------------- chunked scan (32 chunks x 32 steps) ----------------
#define NCH 32
#define CLEN 32

__global__ __launch_bounds__(256) void scan1_kernel(
    const float* __restrict__ DT, const float* __restrict__ XC,
    const float* __restrict__ XDBL, const float* __restrict__ Alog,
    float* __restrict__ HEND, float* __restrict__ PPR)
{
  int j = blockIdx.x >> 2;
  int c = (blockIdx.x & 3) * 256 + threadIdx.x;
  int t0 = j * CLEN;
  __shared__ float Bs[CLEN][16];
  for (int i = threadIdx.x; i < CLEN * 16; i += 256) {
    int r = i >> 4, s = i & 15;
    Bs[r][s] = XDBL[(t0 + r) * 64 + 32 + s];
  }
  float A[16], h[16], Pp[16];
#pragma unroll
  for (int s = 0; s < 16; s++) {
    A[s] = -expf(Alog[c * 16 + s]);
    h[s] = 0.0f; Pp[s] = 1.0f;
  }
  __syncthreads();
  for (int tt = 0; tt < CLEN; tt++) {
    int t = t0 + tt;
    float dtv = DT[(size_t)t * 1024 + c];
    float u = dtv * XC[(size_t)t * 1024 + c];
#pragma unroll
    for (int s = 0; s < 16; s++) {
      float e = expf(dtv * A[s]);
      h[s] = fmaf(h[s], e, u * Bs[tt][s]);
      Pp[s] *= e;
    }
  }
#pragma unroll
  for (int s = 0; s < 16; s++) {
    HEND[(size_t)(j * 1024 + c) * 16 + s] = h[s];
    PPR [(size_t)(j * 1024 + c) * 16 + s] = Pp[s];
  }
}

__global__ __launch_bounds__(256) void scan2_kernel(
    const float* __restrict__ HEND, const float* __restrict__ PPR, float* __restrict__ CIN)
{
  int id = blockIdx.x * 256 + threadIdx.x;
  float carry = 0.0f;
  for (int j = 0; j < NCH; j++) {
    CIN[j * 16384 + id] = carry;
    carry = fmaf(PPR[j * 16384 + id], carry, HEND[j * 16384 + id]);
  }
}

__global__ __launch_bounds__(256) void scan3_kernel(
    const float* __restrict__ DT, const float* __restrict__ XC,
    const float* __restrict__ XDBL, const float* __restrict__ Alog,
    const float* __restrict__ CIN, const float* __restrict__ mD,
    const float* __restrict__ XZ, float* __restrict__ Y)
{
  int j = blockIdx.x >> 2;
  int c = (blockIdx.x & 3) * 256 + threadIdx.x;
  int t0 = j * CLEN;
  __shared__ float Bs[CLEN][16], Cs[CLEN][16];
  for (int i = threadIdx.x; i < CLEN * 16; i += 256) {
    int r = i >> 4, s = i & 15;
    Bs[r][s] = XDBL[(t0 + r) * 64 + 32 + s];
    Cs[r][s] = XDBL[(t0 + r) * 64 + 48 + s];
  }
  float A[16], h[16];
#pragma unroll
  for (int s = 0; s < 16; s++) {
    A[s] = -expf(Alog[c * 16 + s]);
    h[s] = CIN[(size_t)(j * 1024 + c) * 16 + s];
  }
  float dval = mD[c];
  __syncthreads();
  for (int tt = 0; tt < CLEN; tt++) {
    int t = t0 + tt;
    float dtv = DT[(size_t)t * 1024 + c];
    float xcv = XC[(size_t)t * 1024 + c];
    float u = dtv * xcv;
    float y = 0.0f;
#pragma unroll
    for (int s = 0; s < 16; s++) {
      float e = expf(dtv * A[s]);
      h[s] = fmaf(h[s], e, u * Bs[tt][s]);
      y = fmaf(h[s], Cs[tt][s], y);
    }
    float z = XZ[(size_t)t * 2048 + 1024 + c];
    float sz = z / (1.0f + expf(-z));
    Y[(size_t)t * 1024 + c] = (y + dval * xcv) * sz;
  }
}

// ---------------- pooling + head ----------------
__global__ __launch_bounds__(1024) void pool1_kernel(
    const float* __restrict__ XM, const float* __restrict__ pw,
    const float* __restrict__ pb, float* __restrict__ PW)
{
  int t = threadIdx.x;
  float s = pb[0];
  for (int i = 0; i < 512; i++) s = fmaf(XM[(size_t)t * 512 + i], pw[i], s);
  __shared__ float red[1024];
  red[t] = s;
  __syncthreads();
  for (int off = 512; off > 0; off >>= 1) {
    if (t < off) red[t] = fmaxf(red[t], red[t + off]);
    __syncthreads();
  }
  float mx = red[0];
  __syncthreads();
  float e = expf(s - mx);
  red[t] = e;
  __syncthreads();
  for (int off = 512; off > 0; off >>= 1) {
    if (t < off) red[t] = red[t] + red[t + off];
    __syncthreads();
  }
  PW[t] = e / red[0];
}

__global__ __launch_bounds__(256) void pool2_kernel(
    const float* __restrict__ XM, const float* __restrict__ PW, float* __restrict__ HP)
{
  int hcol = blockIdx.x * 256 + threadIdx.x;
  float s = 0.0f;
  for (int tn = 0; tn < 1024; tn++) s = fmaf(PW[tn], XM[(size_t)tn * 512 + hcol], s);
  HP[hcol] = s;
}

__device__ __forceinline__ float blk_reduce_sum_128(float v, float* red){
  int t = threadIdx.x;
#pragma unroll
  for (int off = 32; off; off >>= 1) v += __shfl_xor(v, off);
  __syncthreads();
  if ((t & 63) == 0) red[t >> 6] = v;
  __syncthreads();
  return red[0] + red[1];
}

__global__ __launch_bounds__(128) void head_kernel(
    const float* __restrict__ HP, const float* __restrict__ h1w, const float* __restrict__ h1b,
    const float* __restrict__ g1, const float* __restrict__ be1,
    const float* __restrict__ h2w, const float* __restrict__ h2b,
    const float* __restrict__ g2, const float* __restrict__ be2,
    const float* __restrict__ h3w, const float* __restrict__ h3b,
    float* __restrict__ out)
{
  __shared__ float t1[128];
  __shared__ float red[2];
  int i = threadIdx.x;
  float s = h1b[i];
  for (int k = 0; k < 512; k++) s = fmaf(HP[k], h1w[k * 128 + i], s);
  float mean = blk_reduce_sum_128(s, red) * (1.0f / 128.0f);
  float d = s - mean;
  float var = blk_reduce_sum_128(d * d, red) * (1.0f / 128.0f);
  float x1 = d * rsqrtf(var + 1e-5f) * g1[i] + be1[i];
  x1 = 0.5f * x1 * (1.0f + erff(x1 * 0.70710678118654752f));
  t1[i] = x1;
  __syncthreads();
  s = h2b[i];
  for (int k = 0; k < 128; k++) s = fmaf(t1[k], h2w[k * 128 + i], s);
  mean = blk_reduce_sum_128(s, red) * (1.0f / 128.0f);
  d = s - mean;
  var = blk_reduce_sum_128(d * d, red) * (1.0f / 128.0f);
  float x2 = d * rsqrtf(var + 1e-5f) * g2[i] + be2[i];
  x2 = 0.5f * x2 * (1.0f + erff(x2 * 0.70710678118654752f));
  float tot = blk_reduce_sum_128(x2 * h3w[i], red);
  if (i == 0) out[0] = tot + h3b[0];
}

__global__ __launch_bounds__(256) void copyx_kernel(const float* __restrict__ XM, float* __restrict__ out){
  int i = blockIdx.x * 256 + threadIdx.x;
  out[1 + i] = XM[i];
}

// ---------------- launch ----------------
extern "C" void kernel_launch(void* const* d_in, const int* in_sizes, int n_in,
                              void* d_out, int out_size, void* d_ws, size_t ws_size,
                              hipStream_t stream)
{
  const float* frames   = (const float*)d_in[0];
  const float* fmask    = (const float*)d_in[1];
  const float* in_w     = (const float*)d_in[2];
  const float* in_b     = (const float*)d_in[3];
  const float* pos_emb  = (const float*)d_in[4];
  const float* qkv_w    = (const float*)d_in[5];
  const float* qkv_b    = (const float*)d_in[6];
  const float* ao_w     = (const float*)d_in[7];
  const float* ao_b     = (const float*)d_in[8];
  const float* ln1_g    = (const float*)d_in[9];
  const float* ln1_b    = (const float*)d_in[10];
  const float* ffn_w1   = (const float*)d_in[11];
  const float* ffn_b1   = (const float*)d_in[12];
  const float* ffn_w2   = (const float*)d_in[13];
  const float* ffn_b2   = (const float*)d_in[14];
  const float* ln2_g    = (const float*)d_in[15];
  const float* ln2_b    = (const float*)d_in[16];
  const float* proj_w   = (const float*)d_in[17];
  const float* proj_b   = (const float*)d_in[18];
  const float* m_in_w   = (const float*)d_in[19];
  const float* m_conv_w = (const float*)d_in[20];
  const float* m_conv_b = (const float*)d_in[21];
  const float* m_xproj_w= (const float*)d_in[22];
  const float* m_dt_w   = (const float*)d_in[23];
  const float* m_dt_b   = (const float*)d_in[24];
  const float* m_Alog   = (const float*)d_in[25];
  const float* m_D      = (const float*)d_in[26];
  const float* m_out_w  = (const float*)d_in[27];
  const float* m_ln_g   = (const float*)d_in[28];
  const float* m_ln_b   = (const float*)d_in[29];
  const float* pool_w   = (const float*)d_in[30];
  const float* pool_b   = (const float*)d_in[31];
  const float* h1_w     = (const float*)d_in[32];
  const float* h1_b     = (const float*)d_in[33];
  const float* hg1      = (const float*)d_in[34];
  const float* hb1      = (const float*)d_in[35];
  const float* h2_w     = (const float*)d_in[36];
  const float* h2_b     = (const float*)d_in[37];
  const float* hg2      = (const float*)d_in[38];
  const float* hb2      = (const float*)d_in[39];
  const float* h3_w     = (const float*)d_in[40];
  const float* h3_b     = (const float*)d_in[41];
  float* out = (float*)d_out;

  // ---- workspace: 8 chunks of 128 seqs (8192 rows); total 22.8M floats = 91.2MB
  float* ws = (float*)d_ws;
  float* Xc = ws;                  //  2,097,152  chunk state fp32 (8192 x 256)
  float* QF = Xc + 2097152;        //  6,291,456  QKV fp32 (8192 x 768); mamba overlay
  float* RC = QF + 6291456;        //  2,097,152  residual chunk
  float* FE = RC + 2097152;        //    262,144  frame_emb (1024 x 256)
  float* XM = FE + 262144;         //    524,288  mamba state (1024 x 512)
  float* PW = XM + 524288;         //      2,048
  float* HP = PW + 2048;           //      1,024

  unsigned short* us = (unsigned short*)(ws + 11275264);
  unsigned short* Xhi   = us;                   // 2,097,152 each
  unsigned short* Xlo   = Xhi + 2097152;
  unsigned short* AThi  = Xlo + 2097152;
  unsigned short* ATlo  = AThi + 2097152;
  unsigned short* MIDhi = ATlo + 2097152;       // 4,194,304 each (8192 x 512)
  unsigned short* MIDlo = MIDhi + 4194304;
  unsigned short* Wqkv_hi = MIDlo + 4194304;    // 786,432 (4L x 768 x 256)
  unsigned short* Wqkv_lo = Wqkv_hi + 786432;
  unsigned short* Wao_hi  = Wqkv_lo + 786432;   // 262,144 (4L x 256 x 256)
  unsigned short* Wao_lo  = Wao_hi + 262144;
  unsigned short* Wf1_hi  = Wao_lo + 262144;    // 1,048,576 (4L x 1024 x 256)
  unsigned short* Wf1_lo  = Wf1_hi + 1048576;
  unsigned short* Wf2_hi  = Wf1_lo + 1048576;   // 1,048,576 (4L x 256 x 1024)
  unsigned short* Wf2_lo  = Wf2_hi + 1048576;

  // mamba aliases: overlay QF+RC (8.39M contiguous; encoder done by then)
  float* XZ   = QF;                // 2,097,152 (1024 x 2048)
  float* XC   = QF + 2097152;      // 1,048,576
  float* DT   = QF + 3145728;      // 1,048,576
  float* XDBL = QF + 4194304;      //    65,536
  float* Y    = QF + 4259840;      // 1,048,576
  float* TMP  = QF + 5308416;      //   524,288
  float* HEND = QF + 5832704;      //   524,288
  float* PPR  = QF + 6356992;      //   524,288
  float* CIN  = QF + 6881280;      //   524,288  (ends 7,405,568 < 8,388,608)

  // ---- weight prep: transpose + bf16 split (per launch; ws is re-poisoned) ----
  for (int l = 0; l < 4; l++) {
    wsplit_kernel<<<dim3(24,8),256,0,stream>>>(qkv_w + (size_t)l*256*768, Wqkv_hi + l*196608, Wqkv_lo + l*196608, 256, 768);
    wsplit_kernel<<<dim3(8,8),256,0,stream>>>(ao_w + (size_t)l*256*256, Wao_hi + l*65536, Wao_lo + l*65536, 256, 256);
    wsplit_kernel<<<dim3(32,8),256,0,stream>>>(ffn_w1 + (size_t)l*256*1024, Wf1_hi + l*262144, Wf1_lo + l*262144, 256, 1024);
    wsplit_kernel<<<dim3(8,32),256,0,stream>>>(ffn_w2 + (size_t)l*1024*256, Wf2_hi + l*262144, Wf2_lo + l*262144, 1024, 256);
  }

  // ---- encoder: 8 chunks of 128 sequences, all 4 layers per chunk ----
  for (int ch = 0; ch < 8; ch++) {
    int n0 = ch * 128;
    const float* fch = frames + (size_t)n0 * 64 * 32;
    // embed + pos, fp32 out + bf16 split
    gemm128_kernel<ACT_NONE,0,1,1><<<dim3(2,64),256,0,stream>>>(
        fch, in_w, in_b, pos_emb, Xc, Xhi, Xlo, 32, 32, 256, 256);
    for (int l = 0; l < 4; l++) {
      // QKV (bf16x2 MFMA): out fp32 QF
      gemm_bf16x2_kernel<ACT_NONE,0><<<dim3(6,64),256,0,stream>>>(
          Xhi, Xlo, Wqkv_hi + l*196608, Wqkv_lo + l*196608, qkv_b + l*768,
          QF, nullptr, nullptr, 256, 256, 256, 768);
      // fused attention -> AT hi/lo
      attn_fused_kernel<<<1024,64,0,stream>>>(QF, fmask, AThi, ATlo, n0);
      // out-proj -> RC fp32
      gemm_bf16x2_kernel<ACT_NONE,0><<<dim3(2,64),256,0,stream>>>(
          AThi, ATlo, Wao_hi + l*65536, Wao_lo + l*65536, ao_b + l*256,
          RC, nullptr, nullptr, 256, 256, 256, 256);
      // ln1: X = LN(X + RC), write fp32 + split
      ln_kernel<0,1><<<2048,256,0,stream>>>(Xc, RC, ln1_g + l*256, ln1_b + l*256, Xc, Xhi, Xlo, 256);
      // FFN: two halves of 512
      for (int half = 0; half < 2; half++) {
        gemm_bf16x2_kernel<ACT_GELU,2><<<dim3(4,64),256,0,stream>>>(
            Xhi, Xlo, Wf1_hi + l*262144 + half*131072, Wf1_lo + l*262144 + half*131072,
            ffn_b1 + l*1024 + half*512, nullptr, MIDhi, MIDlo, 256, 256, 256, 512);
        if (half == 0)
          gemm_bf16x2_kernel<ACT_NONE,0><<<dim3(2,64),256,0,stream>>>(
              MIDhi, MIDlo, Wf2_hi + l*262144, Wf2_lo + l*262144, ffn_b2 + l*256,
              RC, nullptr, nullptr, 512, 512, 1024, 256);
        else
          gemm_bf16x2_kernel<ACT_NONE,1><<<dim3(2,64),256,0,stream>>>(
              MIDhi, MIDlo, Wf2_hi + l*262144 + 512, Wf2_lo + l*262144 + 512, nullptr,
              RC, nullptr, nullptr, 512, 512, 1024, 256);
      }
      // ln2
      ln_kernel<0,1><<<2048,256,0,stream>>>(Xc, RC, ln2_g + l*256, ln2_b + l*256, Xc, Xhi, Xlo, 256);
    }
    mean_kernel<<<128,256,0,stream>>>(Xc, fmask, FE, n0);
  }

  gemm64_kernel<ACT_NONE><<<dim3(8,16),256,0,stream>>>(FE, proj_w, proj_b, XM, 256, 256, 512, 512);

  for (int l = 0; l < 8; l++) {
    gemm64_kernel<ACT_NONE><<<dim3(32,16),256,0,stream>>>(
        XM, m_in_w + (size_t)l*512*2048, nullptr, XZ, 512, 512, 2048, 2048);
    conv_kernel<<<4096,256,0,stream>>>(XZ, m_conv_w + l*1024*4, m_conv_b + l*1024, XC);
    gemm64_kernel<ACT_NONE><<<dim3(1,16),256,0,stream>>>(
        XC, m_xproj_w + (size_t)l*1024*64, nullptr, XDBL, 1024, 1024, 64, 64);
    gemm64_kernel<ACT_SOFTPLUS><<<dim3(16,16),256,0,stream>>>(
        XDBL, m_dt_w + (size_t)l*32*1024, m_dt_b + l*1024, DT, 32, 64, 1024, 1024);
    scan1_kernel<<<128,256,0,stream>>>(DT, XC, XDBL, m_Alog + l*16384, HEND, PPR);
    scan2_kernel<<<64,256,0,stream>>>(HEND, PPR, CIN);
    scan3_kernel<<<128,256,0,stream>>>(DT, XC, XDBL, m_Alog + l*16384, CIN, m_D + l*1024, XZ, Y);
    gemm64_kernel<ACT_NONE><<<dim3(8,16),256,0,stream>>>(
        Y, m_out_w + (size_t)l*1024*512, nullptr, TMP, 1024, 1024, 512, 512);
    ln_kernel<1,0><<<256,256,0,stream>>>(TMP, XM, m_ln_g + l*512, m_ln_b + l*512, XM, nullptr, nullptr, 512);
  }

  pool1_kernel<<<1,1024,0,stream>>>(XM, pool_w, pool_b, PW);
  pool2_kernel<<<2,256,0,stream>>>(XM, PW, HP);
  head_kernel<<<1,128,0,stream>>>(HP, h1_w, h1_b, hg1, hb1, h2_w, h2_b, hg2, hb2, h3_w, h3_b, out);
  copyx_kernel<<<2048,256,0,stream>>>(XM, out);
}

// Round 6
// 8594.091 us; speedup vs baseline: 1.6902x; 1.0368x over previous
//
#include <hip/hip_runtime.h>
#include <math.h>

#define ACT_NONE 0
#define ACT_GELU 1
#define ACT_SOFTPLUS 2

template<int ACT>
__device__ __forceinline__ float act_apply(float x){
  if (ACT == ACT_GELU)     return 0.5f * x * (1.0f + erff(x * 0.70710678118654752f));
  if (ACT == ACT_SOFTPLUS) return fmaxf(x, 0.0f) + log1pf(expf(-fabsf(x)));
  return x;
}

// ---------------- bf16 split helpers ----------------
__device__ __forceinline__ unsigned short f2bf(float x){
  unsigned u = __float_as_uint(x);
  u = u + 0x7FFFu + ((u >> 16) & 1u);
  return (unsigned short)(u >> 16);
}
__device__ __forceinline__ float bf2f(unsigned short b){
  return __uint_as_float(((unsigned)b) << 16);
}
__device__ __forceinline__ void bfsplit(float x, unsigned short &hi, unsigned short &lo){
  hi = f2bf(x);
  lo = f2bf(x - bf2f(hi));
}

typedef __attribute__((ext_vector_type(8))) short v8s;
typedef __attribute__((ext_vector_type(4))) float v4f;

// ---------------- bf16x2 MFMA GEMM: 128x128 tile, 256 thr (4 waves) ------------
// A [M][K] bf16 hi/lo; B TRANSPOSED [N][K] bf16 hi/lo.
// OUT: 0 = fp32 store (+bias), 2 = bf16-split store.
template<int ACT, int OUT>
__global__ __launch_bounds__(256) void gemm_bf16x2_kernel(
    const unsigned short* __restrict__ Ahi, const unsigned short* __restrict__ Alo,
    const unsigned short* __restrict__ Bhi, const unsigned short* __restrict__ Blo,
    const float* __restrict__ bias, float* __restrict__ C,
    unsigned short* __restrict__ Chi, unsigned short* __restrict__ Clo,
    int K, int lda, int ldb, int ldc)
{
  __shared__ unsigned short As[2][128][40];   // pad 40 shorts (20 words) -> 2-way max
  __shared__ unsigned short Bs[2][128][40];
  const int tid = threadIdx.x;
  const int m0 = blockIdx.y * 128;
  const int n0 = blockIdx.x * 128;
  const int w = tid >> 6, lane = tid & 63;
  const int wm = (w & 1) * 64, wn = (w >> 1) * 64;
  const int fm = lane & 15, fq = lane >> 4;
  const int r = tid >> 1, h = tid & 1;

  v4f acc[4][4];
#pragma unroll
  for (int i = 0; i < 4; i++)
#pragma unroll
    for (int j = 0; j < 4; j++) acc[i][j] = (v4f){0.f, 0.f, 0.f, 0.f};

  for (int k0 = 0; k0 < K; k0 += 32) {
    const uint4* gah = (const uint4*)(Ahi + (size_t)(m0 + r) * lda + k0 + h * 16);
    const uint4* gal = (const uint4*)(Alo + (size_t)(m0 + r) * lda + k0 + h * 16);
    const uint4* gbh = (const uint4*)(Bhi + (size_t)(n0 + r) * ldb + k0 + h * 16);
    const uint4* gbl = (const uint4*)(Blo + (size_t)(n0 + r) * ldb + k0 + h * 16);
    uint4 ah0 = gah[0], ah1 = gah[1];
    uint4 al0 = gal[0], al1 = gal[1];
    uint4 bh0 = gbh[0], bh1 = gbh[1];
    uint4 bl0 = gbl[0], bl1 = gbl[1];
    __syncthreads();
    *(uint4*)&As[0][r][h * 16]     = ah0;
    *(uint4*)&As[0][r][h * 16 + 8] = ah1;
    *(uint4*)&As[1][r][h * 16]     = al0;
    *(uint4*)&As[1][r][h * 16 + 8] = al1;
    *(uint4*)&Bs[0][r][h * 16]     = bh0;
    *(uint4*)&Bs[0][r][h * 16 + 8] = bh1;
    *(uint4*)&Bs[1][r][h * 16]     = bl0;
    *(uint4*)&Bs[1][r][h * 16 + 8] = bl1;
    __syncthreads();

    v8s ah[4], al[4];
#pragma unroll
    for (int i = 0; i < 4; i++) {
      ah[i] = *(const v8s*)&As[0][wm + i * 16 + fm][fq * 8];
      al[i] = *(const v8s*)&As[1][wm + i * 16 + fm][fq * 8];
    }
#pragma unroll
    for (int j = 0; j < 4; j++) {
      v8s bh = *(const v8s*)&Bs[0][wn + j * 16 + fm][fq * 8];
      v8s bl = *(const v8s*)&Bs[1][wn + j * 16 + fm][fq * 8];
#pragma unroll
      for (int i = 0; i < 4; i++) {
        acc[i][j] = __builtin_amdgcn_mfma_f32_16x16x32_bf16(ah[i], bh, acc[i][j], 0, 0, 0);
        acc[i][j] = __builtin_amdgcn_mfma_f32_16x16x32_bf16(ah[i], bl, acc[i][j], 0, 0, 0);
        acc[i][j] = __builtin_amdgcn_mfma_f32_16x16x32_bf16(al[i], bh, acc[i][j], 0, 0, 0);
      }
    }
  }

#pragma unroll
  for (int i = 0; i < 4; i++)
#pragma unroll
    for (int j = 0; j < 4; j++) {
      int col = n0 + wn + j * 16 + fm;
      float bv = bias ? bias[col] : 0.0f;
#pragma unroll
      for (int reg = 0; reg < 4; reg++) {
        int row = m0 + wm + i * 16 + fq * 4 + reg;
        float v = acc[i][j][reg] + bv;
        v = act_apply<ACT>(v);
        size_t idx = (size_t)row * ldc + col;
        if (OUT == 0) C[idx] = v;
        else { unsigned short hi, lo; bfsplit(v, hi, lo); Chi[idx] = hi; Clo[idx] = lo; }
      }
    }
}

// ------- fused GEMM(bf16x2) + residual + LayerNorm + split write ---------------
// tile 32 rows x 256 cols (full width), 256 thr, wave = 64-col group.
// X <- LN(X + A@B + bias) * g + beta   (X stored as hi/lo bf16 pair, in-place)
__global__ __launch_bounds__(256) void gemm_ln_kernel(
    const unsigned short* __restrict__ Ahi, const unsigned short* __restrict__ Alo,
    const unsigned short* __restrict__ Bhi, const unsigned short* __restrict__ Blo,
    const float* __restrict__ bias,
    const float* __restrict__ g, const float* __restrict__ beta,
    unsigned short* __restrict__ Xhi, unsigned short* __restrict__ Xlo,
    int K, int lda, int ldb)
{
  __shared__ unsigned short As[2][32][40];
  __shared__ unsigned short Bs[2][256][40];
  __shared__ float rs[32][5];
  __shared__ float ms[32][2];
  const int tid = threadIdx.x;
  const int m0 = blockIdx.x * 32;
  const int w = tid >> 6, lane = tid & 63;
  const int fm = lane & 15, fq = lane >> 4;
  const int arow = tid >> 3, asub = tid & 7;
  const int asel = asub >> 2, ac = asub & 3;

  v4f acc[2][4];
#pragma unroll
  for (int i = 0; i < 2; i++)
#pragma unroll
    for (int j = 0; j < 4; j++) acc[i][j] = (v4f){0.f, 0.f, 0.f, 0.f};

  for (int k0 = 0; k0 < K; k0 += 32) {
    const unsigned short* asrc = (asel ? Alo : Ahi) + (size_t)(m0 + arow) * lda + k0 + ac * 8;
    uint4 av = *(const uint4*)asrc;
    const unsigned short* bh = Bhi + (size_t)tid * ldb + k0;
    const unsigned short* bl = Blo + (size_t)tid * ldb + k0;
    uint4 bv[8];
#pragma unroll
    for (int c = 0; c < 4; c++) { bv[c] = *(const uint4*)(bh + c * 8); bv[4 + c] = *(const uint4*)(bl + c * 8); }
    __syncthreads();
    *(uint4*)&As[asel][arow][ac * 8] = av;
#pragma unroll
    for (int c = 0; c < 4; c++) {
      *(uint4*)&Bs[0][tid][c * 8] = bv[c];
      *(uint4*)&Bs[1][tid][c * 8] = bv[4 + c];
    }
    __syncthreads();

    v8s ah[2], al[2];
#pragma unroll
    for (int i = 0; i < 2; i++) {
      ah[i] = *(const v8s*)&As[0][i * 16 + fm][fq * 8];
      al[i] = *(const v8s*)&As[1][i * 16 + fm][fq * 8];
    }
#pragma unroll
    for (int j = 0; j < 4; j++) {
      v8s bhf = *(const v8s*)&Bs[0][w * 64 + j * 16 + fm][fq * 8];
      v8s blf = *(const v8s*)&Bs[1][w * 64 + j * 16 + fm][fq * 8];
#pragma unroll
      for (int i = 0; i < 2; i++) {
        acc[i][j] = __builtin_amdgcn_mfma_f32_16x16x32_bf16(ah[i], bhf, acc[i][j], 0, 0, 0);
        acc[i][j] = __builtin_amdgcn_mfma_f32_16x16x32_bf16(ah[i], blf, acc[i][j], 0, 0, 0);
        acc[i][j] = __builtin_amdgcn_mfma_f32_16x16x32_bf16(al[i], bhf, acc[i][j], 0, 0, 0);
      }
    }
  }

  // p = x_old + delta
  float p[2][4][4];
#pragma unroll
  for (int i = 0; i < 2; i++)
#pragma unroll
    for (int j = 0; j < 4; j++) {
      int cl = w * 64 + j * 16 + fm;
      float bv = bias[cl];
#pragma unroll
      for (int reg = 0; reg < 4; reg++) {
        int rl = i * 16 + fq * 4 + reg;
        size_t idx = (size_t)(m0 + rl) * 256 + cl;
        float xo = bf2f(Xhi[idx]) + bf2f(Xlo[idx]);
        p[i][j][reg] = xo + acc[i][j][reg] + bv;
      }
    }
  // pass 1: mean
#pragma unroll
  for (int i = 0; i < 2; i++)
#pragma unroll
    for (int reg = 0; reg < 4; reg++) {
      float s = p[i][0][reg] + p[i][1][reg] + p[i][2][reg] + p[i][3][reg];
      s += __shfl_xor(s, 1); s += __shfl_xor(s, 2);
      s += __shfl_xor(s, 4); s += __shfl_xor(s, 8);
      if (fm == 0) rs[i * 16 + fq * 4 + reg][w] = s;
    }
  __syncthreads();
  if (tid < 32) ms[tid][0] = (rs[tid][0] + rs[tid][1] + rs[tid][2] + rs[tid][3]) * (1.0f / 256.0f);
  __syncthreads();
  // pass 2: var
#pragma unroll
  for (int i = 0; i < 2; i++)
#pragma unroll
    for (int reg = 0; reg < 4; reg++) {
      int rl = i * 16 + fq * 4 + reg;
      float mean = ms[rl][0];
      float s = 0.0f;
#pragma unroll
      for (int j = 0; j < 4; j++) { float d = p[i][j][reg] - mean; s += d * d; }
      s += __shfl_xor(s, 1); s += __shfl_xor(s, 2);
      s += __shfl_xor(s, 4); s += __shfl_xor(s, 8);
      if (fm == 0) rs[rl][w] = s;
    }
  __syncthreads();
  if (tid < 32) {
    float var = (rs[tid][0] + rs[tid][1] + rs[tid][2] + rs[tid][3]) * (1.0f / 256.0f);
    ms[tid][1] = rsqrtf(var + 1e-5f);
  }
  __syncthreads();
#pragma unroll
  for (int i = 0; i < 2; i++)
#pragma unroll
    for (int j = 0; j < 4; j++) {
      int cl = w * 64 + j * 16 + fm;
      float gv = g[cl], bv = beta[cl];
#pragma unroll
      for (int reg = 0; reg < 4; reg++) {
        int rl = i * 16 + fq * 4 + reg;
        float t = (p[i][j][reg] - ms[rl][0]) * ms[rl][1] * gv + bv;
        size_t idx = (size_t)(m0 + rl) * 256 + cl;
        unsigned short hi, lo; bfsplit(t, hi, lo);
        Xhi[idx] = hi; Xlo[idx] = lo;
      }
    }
}

// -------- weight transpose + split (batched over layers via blockIdx.z) --------
__global__ __launch_bounds__(256) void wsplit_kernel(
    const float* __restrict__ W, unsigned short* __restrict__ Whi,
    unsigned short* __restrict__ Wlo, int K, int N, size_t wstride, size_t ostride)
{
  __shared__ float tile[32][33];
  const float* Wl = W + blockIdx.z * wstride;
  unsigned short* Whl = Whi + blockIdx.z * ostride;
  unsigned short* Wll = Wlo + blockIdx.z * ostride;
  int k0 = blockIdx.y * 32, n0 = blockIdx.x * 32;
  int t = threadIdx.x;
  int tn = t & 31, tk8 = t >> 5;
#pragma unroll
  for (int i = 0; i < 4; i++) {
    int k = tk8 + i * 8;
    tile[k][tn] = Wl[(size_t)(k0 + k) * N + n0 + tn];
  }
  __syncthreads();
  int tk = t & 31, tn8 = t >> 5;
#pragma unroll
  for (int i = 0; i < 4; i++) {
    int n = tn8 + i * 8;
    float v = tile[tk][n];
    unsigned short hi, lo; bfsplit(v, hi, lo);
    size_t idx = (size_t)(n0 + n) * K + k0 + tk;
    Whl[idx] = hi; Wll[idx] = lo;
  }
}

// ------------- fp32 GEMM 128x128 (embed only), POS + split write ---------------
template<int ACT, int POS, int SPLIT>
__global__ __launch_bounds__(256) void gemm128_kernel(
    const float* __restrict__ A, const float* __restrict__ W,
    const float* __restrict__ bias, const float* __restrict__ pos,
    float* __restrict__ C, unsigned short* __restrict__ Chi, unsigned short* __restrict__ Clo,
    int K, int lda, int ldw, int ldc)
{
  __shared__ float As[16][128];
  __shared__ float Ws[16][128];
  const int tid = threadIdx.x;
  const int m0 = blockIdx.y * 128;
  const int n0 = blockIdx.x * 128;
  const int tx = tid & 15, ty = tid >> 4;
  const int ar = tid >> 2, ak = (tid & 3) * 4;
  const int wk = tid >> 5, wn = (tid & 31) * 4;

  float acc[8][8];
#pragma unroll
  for (int i = 0; i < 8; i++)
#pragma unroll
    for (int j = 0; j < 8; j++) acc[i][j] = 0.0f;

  for (int k0 = 0; k0 < K; k0 += 16) {
    float4 a0 = *(const float4*)(A + (size_t)(m0 + ar)      * lda + k0 + ak);
    float4 a1 = *(const float4*)(A + (size_t)(m0 + ar + 64) * lda + k0 + ak);
    float4 w0 = *(const float4*)(W + (size_t)(k0 + wk)     * ldw + n0 + wn);
    float4 w1 = *(const float4*)(W + (size_t)(k0 + wk + 8) * ldw + n0 + wn);
    __syncthreads();
    As[ak + 0][ar] = a0.x; As[ak + 1][ar] = a0.y; As[ak + 2][ar] = a0.z; As[ak + 3][ar] = a0.w;
    As[ak + 0][ar + 64] = a1.x; As[ak + 1][ar + 64] = a1.y; As[ak + 2][ar + 64] = a1.z; As[ak + 3][ar + 64] = a1.w;
    *(float4*)&Ws[wk][wn] = w0;
    *(float4*)&Ws[wk + 8][wn] = w1;
    __syncthreads();
#pragma unroll
    for (int k = 0; k < 16; k++) {
      float4 xa = *(float4*)&As[k][ty * 8];
      float4 xb = *(float4*)&As[k][ty * 8 + 4];
      float4 y0 = *(float4*)&Ws[k][tx * 8];
      float4 y1 = *(float4*)&Ws[k][tx * 8 + 4];
      float a8[8] = {xa.x, xa.y, xa.z, xa.w, xb.x, xb.y, xb.z, xb.w};
      float b8[8] = {y0.x, y0.y, y0.z, y0.w, y1.x, y1.y, y1.z, y1.w};
#pragma unroll
      for (int i = 0; i < 8; i++)
#pragma unroll
        for (int j = 0; j < 8; j++) acc[i][j] = fmaf(a8[i], b8[j], acc[i][j]);
    }
  }
#pragma unroll
  for (int i = 0; i < 8; i++) {
    int row = m0 + ty * 8 + i;
    float* cp = C + (size_t)row * ldc + n0 + tx * 8;
    float v[8];
#pragma unroll
    for (int j = 0; j < 8; j++) {
      float t = acc[i][j];
      int col = n0 + tx * 8 + j;
      if (bias) t += bias[col];
      if (POS)  t += pos[(row & 63) * 256 + col];
      t = act_apply<ACT>(t);
      v[j] = t;
      if (SPLIT) {
        unsigned short hi, lo; bfsplit(t, hi, lo);
        size_t idx = (size_t)row * ldc + col;
        Chi[idx] = hi; Clo[idx] = lo;
      }
    }
    *(float4*)cp       = make_float4(v[0], v[1], v[2], v[3]);
    *(float4*)(cp + 4) = make_float4(v[4], v[5], v[6], v[7]);
  }
}

// ---------------- GEMM 64x64 tile fp32 (mamba) ----------------
template<int ACT>
__global__ __launch_bounds__(256) void gemm64_kernel(
    const float* __restrict__ A, const float* __restrict__ W,
    const float* __restrict__ bias, float* __restrict__ C,
    int K, int lda, int ldw, int ldc)
{
  __shared__ float As[16][64];
  __shared__ float Ws[16][64];
  const int tid = threadIdx.x;
  const int m0 = blockIdx.y * 64;
  const int n0 = blockIdx.x * 64;
  const int tx = tid & 15, ty = tid >> 4;
  const int ar = tid >> 2, ak = (tid & 3) * 4;
  const int wk = tid >> 4, wn = (tid & 15) * 4;

  float acc[4][4];
#pragma unroll
  for (int i = 0; i < 4; i++)
#pragma unroll
    for (int j = 0; j < 4; j++) acc[i][j] = 0.0f;

  for (int k0 = 0; k0 < K; k0 += 16) {
    float4 a0 = *(const float4*)(A + (size_t)(m0 + ar) * lda + k0 + ak);
    float4 w0 = *(const float4*)(W + (size_t)(k0 + wk) * ldw + n0 + wn);
    __syncthreads();
    As[ak + 0][ar] = a0.x; As[ak + 1][ar] = a0.y; As[ak + 2][ar] = a0.z; As[ak + 3][ar] = a0.w;
    *(float4*)&Ws[wk][wn] = w0;
    __syncthreads();
#pragma unroll
    for (int k = 0; k < 16; k++) {
      float4 xa = *(float4*)&As[k][ty * 4];
      float4 yb = *(float4*)&Ws[k][tx * 4];
      float a4[4] = {xa.x, xa.y, xa.z, xa.w};
      float b4[4] = {yb.x, yb.y, yb.z, yb.w};
#pragma unroll
      for (int i = 0; i < 4; i++)
#pragma unroll
        for (int j = 0; j < 4; j++) acc[i][j] = fmaf(a4[i], b4[j], acc[i][j]);
    }
  }
#pragma unroll
  for (int i = 0; i < 4; i++) {
    float* cp = C + (size_t)(m0 + ty * 4 + i) * ldc + n0 + tx * 4;
    float v[4];
#pragma unroll
    for (int j = 0; j < 4; j++) {
      float t = acc[i][j];
      if (bias) t += bias[n0 + tx * 4 + j];
      v[j] = act_apply<ACT>(t);
    }
    *(float4*)cp = make_float4(v[0], v[1], v[2], v[3]);
  }
}

// ---------------- fused attention; writes bf16-split AT ----------------
__global__ __launch_bounds__(64) void attn_fused_kernel(
    const float* __restrict__ QKVc, const float* __restrict__ mask,
    unsigned short* __restrict__ AThi, unsigned short* __restrict__ ATlo, int n0)
{
  int bid = blockIdx.x;
  int nl = bid >> 3;
  int h = bid & 7;
  int n = n0 + nl;
  int tid = threadIdx.x;
  int tx = tid & 7, ty = tid >> 3;
  __shared__ float Qt[32][68];
  __shared__ float Kt[32][68];
  __shared__ float Vs[64][36];
  __shared__ float Pt[64][68];
  __shared__ float bs[64];
  const float* base = QKVc + (size_t)nl * (64 * 768);
#pragma unroll
  for (int i = 0; i < 32; i++) {
    int idx = tid + i * 64;
    int bar = idx >> 5, c = idx & 31;
    Qt[c][bar] = base[bar * 768 + h * 32 + c];
    Kt[c][bar] = base[bar * 768 + 256 + h * 32 + c];
    Vs[bar][c] = base[bar * 768 + 512 + h * 32 + c];
  }
  bs[tid] = (1.0f - mask[n * 64 + tid]) * -1e9f;
  __syncthreads();
  float acc[8][8] = {};
  for (int c = 0; c < 32; c++) {
    float4 ax = *(float4*)&Qt[c][ty * 8];
    float4 ay = *(float4*)&Qt[c][ty * 8 + 4];
    float4 bx = *(float4*)&Kt[c][tx * 8];
    float4 by = *(float4*)&Kt[c][tx * 8 + 4];
    float a8[8] = {ax.x, ax.y, ax.z, ax.w, ay.x, ay.y, ay.z, ay.w};
    float b8[8] = {bx.x, bx.y, bx.z, bx.w, by.x, by.y, by.z, by.w};
#pragma unroll
    for (int i = 0; i < 8; i++)
#pragma unroll
      for (int j = 0; j < 8; j++) acc[i][j] = fmaf(a8[i], b8[j], acc[i][j]);
  }
  const float scale = 0.17677669529663687f;
#pragma unroll
  for (int i = 0; i < 8; i++) {
    float s[8];
    float mx = -3.0e38f;
#pragma unroll
    for (int j = 0; j < 8; j++) { s[j] = acc[i][j] * scale + bs[tx * 8 + j]; mx = fmaxf(mx, s[j]); }
#pragma unroll
    for (int off = 1; off < 8; off <<= 1) mx = fmaxf(mx, __shfl_xor(mx, off));
    float sum = 0.0f;
#pragma unroll
    for (int j = 0; j < 8; j++) { s[j] = expf(s[j] - mx); sum += s[j]; }
#pragma unroll
    for (int off = 1; off < 8; off <<= 1) sum += __shfl_xor(sum, off);
    float inv = 1.0f / sum;
#pragma unroll
    for (int j = 0; j < 8; j++) Pt[tx * 8 + j][ty * 8 + i] = s[j] * inv;
  }
  __syncthreads();
  float o[8][4] = {};
  for (int j = 0; j < 64; j++) {
    float4 px = *(float4*)&Pt[j][ty * 8];
    float4 py = *(float4*)&Pt[j][ty * 8 + 4];
    float4 v  = *(float4*)&Vs[j][tx * 4];
    float p8[8] = {px.x, px.y, px.z, px.w, py.x, py.y, py.z, py.w};
#pragma unroll
    for (int i = 0; i < 8; i++) {
      o[i][0] = fmaf(p8[i], v.x, o[i][0]);
      o[i][1] = fmaf(p8[i], v.y, o[i][1]);
      o[i][2] = fmaf(p8[i], v.z, o[i][2]);
      o[i][3] = fmaf(p8[i], v.w, o[i][3]);
    }
  }
#pragma unroll
  for (int i = 0; i < 8; i++) {
    size_t base_o = (size_t)(nl * 64 + ty * 8 + i) * 256 + h * 32 + tx * 4;
#pragma unroll
    for (int c = 0; c < 4; c++) {
      unsigned short hi, lo; bfsplit(o[i][c], hi, lo);
      AThi[base_o + c] = hi; ATlo[base_o + c] = lo;
    }
  }
}

// ---------------- LayerNorm wave-per-row (mamba): o = LN(a)*g+beta + b ----------
__global__ __launch_bounds__(256) void ln_res_kernel(
    const float* __restrict__ a, const float* __restrict__ b,
    const float* __restrict__ g, const float* __restrict__ beta,
    float* __restrict__ o, int Wd)
{
  int wave = threadIdx.x >> 6;
  int lane = threadIdx.x & 63;
  int row = blockIdx.x * 4 + wave;
  int P = Wd >> 6;
  const float* ar = a + (size_t)row * Wd;
  const float* br = b + (size_t)row * Wd;
  float v[8];
  float s = 0.0f;
  for (int i = 0; i < P; i++) { float x = ar[lane + i * 64]; v[i] = x; s += x; }
#pragma unroll
  for (int off = 32; off; off >>= 1) s += __shfl_xor(s, off);
  float mean = s / Wd;
  float vs = 0.0f;
  for (int i = 0; i < P; i++) { float d = v[i] - mean; vs += d * d; }
#pragma unroll
  for (int off = 32; off; off >>= 1) vs += __shfl_xor(vs, off);
  float rstd = rsqrtf(vs / Wd + 1e-5f);
  for (int i = 0; i < P; i++) {
    int col = lane + i * 64;
    o[(size_t)row * Wd + col] = (v[i] - mean) * rstd * g[col] + beta[col] + br[col];
  }
}

// ------------- masked mean over bars (reads hi/lo X) ---------------------------
__global__ __launch_bounds__(256) void mean_kernel(
    const unsigned short* __restrict__ Xhi, const unsigned short* __restrict__ Xlo,
    const float* __restrict__ mask, float* __restrict__ FE, int n0)
{
  int n = blockIdx.x;
  int c = threadIdx.x;
  float s = 0.0f, ms = 0.0f;
  for (int bar = 0; bar < 64; bar++) {
    float mk = mask[(n0 + n) * 64 + bar];
    size_t idx = (size_t)(n * 64 + bar) * 256 + c;
    s = fmaf(bf2f(Xhi[idx]) + bf2f(Xlo[idx]), mk, s);
    ms += mk;
  }
  FE[(n0 + n) * 256 + c] = s / fmaxf(ms, 1.0f);
}

// ---------------- mamba conv (4-tap causal) + silu ----------------
__global__ __launch_bounds__(256) void conv_kernel(
    const float* __restrict__ XZ, const float* __restrict__ w,
    const float* __restrict__ b, float* __restrict__ XC)
{
  int idx = blockIdx.x * 256 + threadIdx.x;
  int t = idx >> 10, c = idx & 1023;
  float acc = b[c];
  const float* wc = w + c * 4;
#pragma unroll
  for (int k = 0; k < 4; k++) {
    int tt = t + k - 3;
    if (tt >= 0) acc = fmaf(XZ[(size_t)tt * 2048 + c], wc[k], acc);
  }
  XC[idx] = acc / (1.0f + expf(-acc));
}

// ---------------- chunked scan (32 chunks x 32 steps) ----------------
#define NCH 32
#define CLEN 32

__global__ __launch_bounds__(256) void scan1_kernel(
    const float* __restrict__ DT, const float* __restrict__ XC,
    const float* __restrict__ XDBL, const float* __restrict__ Alog,
    float* __restrict__ HEND, float* __restrict__ PPR)
{
  int j = blockIdx.x >> 2;
  int c = (blockIdx.x & 3) * 256 + threadIdx.x;
  int t0 = j * CLEN;
  __shared__ float Bs[CLEN][16];
  for (int i = threadIdx.x; i < CLEN * 16; i += 256) {
    int r = i >> 4, s = i & 15;
    Bs[r][s] = XDBL[(t0 + r) * 64 + 32 + s];
  }
  float A[16], h[16], Pp[16];
#pragma unroll
  for (int s = 0; s < 16; s++) {
    A[s] = -expf(Alog[c * 16 + s]);
    h[s] = 0.0f; Pp[s] = 1.0f;
  }
  __syncthreads();
  for (int tt = 0; tt < CLEN; tt++) {
    int t = t0 + tt;
    float dtv = DT[(size_t)t * 1024 + c];
    float u = dtv * XC[(size_t)t * 1024 + c];
#pragma unroll
    for (int s = 0; s < 16; s++) {
      float e = expf(dtv * A[s]);
      h[s] = fmaf(h[s], e, u * Bs[tt][s]);
      Pp[s] *= e;
    }
  }
#pragma unroll
  for (int s = 0; s < 16; s++) {
    HEND[(size_t)(j * 1024 + c) * 16 + s] = h[s];
    PPR [(size_t)(j * 1024 + c) * 16 + s] = Pp[s];
  }
}

__global__ __launch_bounds__(256) void scan2_kernel(
    const float* __restrict__ HEND, const float* __restrict__ PPR, float* __restrict__ CIN)
{
  int id = blockIdx.x * 256 + threadIdx.x;
  float carry = 0.0f;
  for (int j = 0; j < NCH; j++) {
    CIN[j * 16384 + id] = carry;
    carry = fmaf(PPR[j * 16384 + id], carry, HEND[j * 16384 + id]);
  }
}

__global__ __launch_bounds__(256) void scan3_kernel(
    const float* __restrict__ DT, const float* __restrict__ XC,
    const float* __restrict__ XDBL, const float* __restrict__ Alog,
    const float* __restrict__ CIN, const float* __restrict__ mD,
    const float* __restrict__ XZ, float* __restrict__ Y)
{
  int j = blockIdx.x >> 2;
  int c = (blockIdx.x & 3) * 256 + threadIdx.x;
  int t0 = j * CLEN;
  __shared__ float Bs[CLEN][16], Cs[CLEN][16];
  for (int i = threadIdx.x; i < CLEN * 16; i += 256) {
    int r = i >> 4, s = i & 15;
    Bs[r][s] = XDBL[(t0 + r) * 64 + 32 + s];
    Cs[r][s] = XDBL[(t0 + r) * 64 + 48 + s];
  }
  float A[16], h[16];
#pragma unroll
  for (int s = 0; s < 16; s++) {
    A[s] = -expf(Alog[c * 16 + s]);
    h[s] = CIN[(size_t)(j * 1024 + c) * 16 + s];
  }
  float dval = mD[c];
  __syncthreads();
  for (int tt = 0; tt < CLEN; tt++) {
    int t = t0 + tt;
    float dtv = DT[(size_t)t * 1024 + c];
    float xcv = XC[(size_t)t * 1024 + c];
    float u = dtv * xcv;
    float y = 0.0f;
#pragma unroll
    for (int s = 0; s < 16; s++) {
      float e = expf(dtv * A[s]);
      h[s] = fmaf(h[s], e, u * Bs[tt][s]);
      y = fmaf(h[s], Cs[tt][s], y);
    }
    float z = XZ[(size_t)t * 2048 + 1024 + c];
    float sz = z / (1.0f + expf(-z));
    Y[(size_t)t * 1024 + c] = (y + dval * xcv) * sz;
  }
}

// ---------------- pooling + head ----------------
__global__ __launch_bounds__(1024) void pool1_kernel(
    const float* __restrict__ XM, const float* __restrict__ pw,
    const float* __restrict__ pb, float* __restrict__ PW)
{
  int t = threadIdx.x;
  float s = pb[0];
  for (int i = 0; i < 512; i++) s = fmaf(XM[(size_t)t * 512 + i], pw[i], s);
  __shared__ float red[1024];
  red[t] = s;
  __syncthreads();
  for (int off = 512; off > 0; off >>= 1) {
    if (t < off) red[t] = fmaxf(red[t], red[t + off]);
    __syncthreads();
  }
  float mx = red[0];
  __syncthreads();
  float e = expf(s - mx);
  red[t] = e;
  __syncthreads();
  for (int off = 512; off > 0; off >>= 1) {
    if (t < off) red[t] = red[t] + red[t + off];
    __syncthreads();
  }
  PW[t] = e / red[0];
}

__global__ __launch_bounds__(256) void pool2_kernel(
    const float* __restrict__ XM, const float* __restrict__ PW, float* __restrict__ HP)
{
  int hcol = blockIdx.x * 256 + threadIdx.x;
  float s = 0.0f;
  for (int tn = 0; tn < 1024; tn++) s = fmaf(PW[tn], XM[(size_t)tn * 512 + hcol], s);
  HP[hcol] = s;
}

__device__ __forceinline__ float blk_reduce_sum_128(float v, float* red){
  int t = threadIdx.x;
#pragma unroll
  for (int off = 32; off; off >>= 1) v += __shfl_xor(v, off);
  __syncthreads();
  if ((t & 63) == 0) red[t >> 6] = v;
  __syncthreads();
  return red[0] + red[1];
}

__global__ __launch_bounds__(128) void head_kernel(
    const float* __restrict__ HP, const float* __restrict__ h1w, const float* __restrict__ h1b,
    const float* __restrict__ g1, const float* __restrict__ be1,
    const float* __restrict__ h2w, const float* __restrict__ h2b,
    const float* __restrict__ g2, const float* __restrict__ be2,
    const float* __restrict__ h3w, const float* __restrict__ h3b,
    float* __restrict__ out)
{
  __shared__ float t1[128];
  __shared__ float red[2];
  int i = threadIdx.x;
  float s = h1b[i];
  for (int k = 0; k < 512; k++) s = fmaf(HP[k], h1w[k * 128 + i], s);
  float mean = blk_reduce_sum_128(s, red) * (1.0f / 128.0f);
  float d = s - mean;
  float var = blk_reduce_sum_128(d * d, red) * (1.0f / 128.0f);
  float x1 = d * rsqrtf(var + 1e-5f) * g1[i] + be1[i];
  x1 = 0.5f * x1 * (1.0f + erff(x1 * 0.70710678118654752f));
  t1[i] = x1;
  __syncthreads();
  s = h2b[i];
  for (int k = 0; k < 128; k++) s = fmaf(t1[k], h2w[k * 128 + i], s);
  mean = blk_reduce_sum_128(s, red) * (1.0f / 128.0f);
  d = s - mean;
  var = blk_reduce_sum_128(d * d, red) * (1.0f / 128.0f);
  float x2 = d * rsqrtf(var + 1e-5f) * g2[i] + be2[i];
  x2 = 0.5f * x2 * (1.0f + erff(x2 * 0.70710678118654752f));
  float tot = blk_reduce_sum_128(x2 * h3w[i], red);
  if (i == 0) out[0] = tot + h3b[0];
}

__global__ __launch_bounds__(256) void copyx_kernel(const float* __restrict__ XM, float* __restrict__ out){
  int i = blockIdx.x * 256 + threadIdx.x;
  out[1 + i] = XM[i];
}

// ---------------- launch ----------------
extern "C" void kernel_launch(void* const* d_in, const int* in_sizes, int n_in,
                              void* d_out, int out_size, void* d_ws, size_t ws_size,
                              hipStream_t stream)
{
  const float* frames   = (const float*)d_in[0];
  const float* fmask    = (const float*)d_in[1];
  const float* in_w     = (const float*)d_in[2];
  const float* in_b     = (const float*)d_in[3];
  const float* pos_emb  = (const float*)d_in[4];
  const float* qkv_w    = (const float*)d_in[5];
  const float* qkv_b    = (const float*)d_in[6];
  const float* ao_w     = (const float*)d_in[7];
  const float* ao_b     = (const float*)d_in[8];
  const float* ln1_g    = (const float*)d_in[9];
  const float* ln1_b    = (const float*)d_in[10];
  const float* ffn_w1   = (const float*)d_in[11];
  const float* ffn_b1   = (const float*)d_in[12];
  const float* ffn_w2   = (const float*)d_in[13];
  const float* ffn_b2   = (const float*)d_in[14];
  const float* ln2_g    = (const float*)d_in[15];
  const float* ln2_b    = (const float*)d_in[16];
  const float* proj_w   = (const float*)d_in[17];
  const float* proj_b   = (const float*)d_in[18];
  const float* m_in_w   = (const float*)d_in[19];
  const float* m_conv_w = (const float*)d_in[20];
  const float* m_conv_b = (const float*)d_in[21];
  const float* m_xproj_w= (const float*)d_in[22];
  const float* m_dt_w   = (const float*)d_in[23];
  const float* m_dt_b   = (const float*)d_in[24];
  const float* m_Alog   = (const float*)d_in[25];
  const float* m_D      = (const float*)d_in[26];
  const float* m_out_w  = (const float*)d_in[27];
  const float* m_ln_g   = (const float*)d_in[28];
  const float* m_ln_b   = (const float*)d_in[29];
  const float* pool_w   = (const float*)d_in[30];
  const float* pool_b   = (const float*)d_in[31];
  const float* h1_w     = (const float*)d_in[32];
  const float* h1_b     = (const float*)d_in[33];
  const float* hg1      = (const float*)d_in[34];
  const float* hb1      = (const float*)d_in[35];
  const float* h2_w     = (const float*)d_in[36];
  const float* h2_b     = (const float*)d_in[37];
  const float* hg2      = (const float*)d_in[38];
  const float* hb2      = (const float*)d_in[39];
  const float* h3_w     = (const float*)d_in[40];
  const float* h3_b     = (const float*)d_in[41];
  float* out = (float*)d_out;

  // ---- workspace layout (floats), total 24,906,752 = 99.6 MB ----
  // Union region B = 16,777,216 floats:
  //   phase QKV/attn : QF fp32 (12,582,912) | AThi/ATlo shorts (4,194,304 each)
  //   phase FFN      : MIDhi/MIDlo shorts (16,777,216 each) -- exactly fills B
  //   phase mamba    : XZ..CIN overlay (7,405,568 floats)
  float* ws = (float*)d_ws;
  float* B  = ws;
  float* QF = B;                                       // 12,582,912 floats
  unsigned short* AThi = (unsigned short*)(B + 12582912);  // 4,194,304 shorts
  unsigned short* ATlo = AThi + 4194304;                   // ends exactly at B+16,777,216 floats
  unsigned short* MIDhi = (unsigned short*)B;              // 16,777,216 shorts
  unsigned short* MIDlo = MIDhi + 16777216;                // ends exactly at B+16,777,216 floats

  unsigned short* Xhi = (unsigned short*)(ws + 16777216);  // 4,194,304 shorts
  unsigned short* Xlo = Xhi + 4194304;                     // region = 4,194,304 floats

  unsigned short* Wqkv_hi = (unsigned short*)(ws + 20971520); // 786,432
  unsigned short* Wqkv_lo = Wqkv_hi + 786432;
  unsigned short* Wao_hi  = Wqkv_lo + 786432;    // 262,144
  unsigned short* Wao_lo  = Wao_hi + 262144;
  unsigned short* Wf1_hi  = Wao_lo + 262144;     // 1,048,576
  unsigned short* Wf1_lo  = Wf1_hi + 1048576;
  unsigned short* Wf2_hi  = Wf1_lo + 1048576;    // 1,048,576
  unsigned short* Wf2_lo  = Wf2_hi + 1048576;    // ends at ws + 24,117,248 floats

  float* FE = ws + 24117248;         //   262,144
  float* XM = FE + 262144;           //   524,288
  float* PW = XM + 524288;           //     2,048
  float* HP = PW + 2048;             //     1,024  (total 24,906,752)

  // mamba aliases overlay B
  float* XZ   = B;                 // 2,097,152 (1024x2048)
  float* XC   = B + 2097152;       // 1,048,576
  float* DT   = B + 3145728;       // 1,048,576
  float* XDBL = B + 4194304;       //    65,536
  float* Y    = B + 4259840;       // 1,048,576
  float* TMP  = B + 5308416;       //   524,288
  float* HEND = B + 5832704;       //   524,288
  float* PPR  = B + 6356992;       //   524,288
  float* CIN  = B + 6881280;       //   524,288 (ends 7,405,568 < 16,777,216)

  // ---- weight prep: 4 batched launches (z = layer) ----
  wsplit_kernel<<<dim3(24,8,4),256,0,stream>>>(qkv_w, Wqkv_hi, Wqkv_lo, 256, 768, 196608, 196608);
  wsplit_kernel<<<dim3(8,8,4),256,0,stream>>>(ao_w, Wao_hi, Wao_lo, 256, 256, 65536, 65536);
  wsplit_kernel<<<dim3(32,8,4),256,0,stream>>>(ffn_w1, Wf1_hi, Wf1_lo, 256, 1024, 262144, 262144);
  wsplit_kernel<<<dim3(8,32,4),256,0,stream>>>(ffn_w2, Wf2_hi, Wf2_lo, 1024, 256, 262144, 262144);

  // ---- encoder: 4 chunks of 256 sequences (16384 rows) ----
  for (int ch = 0; ch < 4; ch++) {
    int n0 = ch * 256;
    const float* fch = frames + (size_t)n0 * 64 * 32;
    // embed + pos -> X hi/lo (fp32 scratch into QF; 16384x256 fits)
    gemm128_kernel<ACT_NONE,1,1><<<dim3(2,128),256,0,stream>>>(
        fch, in_w, in_b, pos_emb, QF, Xhi, Xlo, 32, 32, 256, 256);
    for (int l = 0; l < 4; l++) {
      // QKV -> QF fp32
      gemm_bf16x2_kernel<ACT_NONE,0><<<dim3(6,128),256,0,stream>>>(
          Xhi, Xlo, Wqkv_hi + l*196608, Wqkv_lo + l*196608, qkv_b + l*768,
          QF, nullptr, nullptr, 256, 256, 256, 768);
      // attention -> AT hi/lo
      attn_fused_kernel<<<2048,64,0,stream>>>(QF, fmask, AThi, ATlo, n0);
      // out-proj + residual + LN1 (in-place on X)
      gemm_ln_kernel<<<512,256,0,stream>>>(
          AThi, ATlo, Wao_hi + l*65536, Wao_lo + l*65536, ao_b + l*256,
          ln1_g + l*256, ln1_b + l*256, Xhi, Xlo, 256, 256, 256);
      // FFN1 (full N=1024) -> MID hi/lo (overlays QF+AT, both dead)
      gemm_bf16x2_kernel<ACT_GELU,2><<<dim3(8,128),256,0,stream>>>(
          Xhi, Xlo, Wf1_hi + l*262144, Wf1_lo + l*262144, ffn_b1 + l*1024,
          nullptr, MIDhi, MIDlo, 256, 256, 256, 1024);
      // FFN2 + residual + LN2 (in-place on X)
      gemm_ln_kernel<<<512,256,0,stream>>>(
          MIDhi, MIDlo, Wf2_hi + l*262144, Wf2_lo + l*262144, ffn_b2 + l*256,
          ln2_g + l*256, ln2_b + l*256, Xhi, Xlo, 1024, 1024, 1024);
    }
    mean_kernel<<<256,256,0,stream>>>(Xhi, Xlo, fmask, FE, n0);
  }

  gemm64_kernel<ACT_NONE><<<dim3(8,16),256,0,stream>>>(FE, proj_w, proj_b, XM, 256, 256, 512, 512);

  for (int l = 0; l < 8; l++) {
    gemm64_kernel<ACT_NONE><<<dim3(32,16),256,0,stream>>>(
        XM, m_in_w + (size_t)l*512*2048, nullptr, XZ, 512, 512, 2048, 2048);
    conv_kernel<<<4096,256,0,stream>>>(XZ, m_conv_w + l*1024*4, m_conv_b + l*1024, XC);
    gemm64_kernel<ACT_NONE><<<dim3(1,16),256,0,stream>>>(
        XC, m_xproj_w + (size_t)l*1024*64, nullptr, XDBL, 1024, 1024, 64, 64);
    gemm64_kernel<ACT_SOFTPLUS><<<dim3(16,16),256,0,stream>>>(
        XDBL, m_dt_w + (size_t)l*32*1024, m_dt_b + l*1024, DT, 32, 64, 1024, 1024);
    scan1_kernel<<<128,256,0,stream>>>(DT, XC, XDBL, m_Alog + l*16384, HEND, PPR);
    scan2_kernel<<<64,256,0,stream>>>(HEND, PPR, CIN);
    scan3_kernel<<<128,256,0,stream>>>(DT, XC, XDBL, m_Alog + l*16384, CIN, m_D + l*1024, XZ, Y);
    gemm64_kernel<ACT_NONE><<<dim3(8,16),256,0,stream>>>(
        Y, m_out_w + (size_t)l*1024*512, nullptr, TMP, 1024, 1024, 512, 512);
    ln_res_kernel<<<256,256,0,stream>>>(TMP, XM, m_ln_g + l*512, m_ln_b + l*512, XM, 512);
  }

  pool1_kernel<<<1,1024,0,stream>>>(XM, pool_w, pool_b, PW);
  pool2_kernel<<<2,256,0,stream>>>(XM, PW, HP);
  head_kernel<<<1,128,0,stream>>>(HP, h1_w, h1_b, hg1, hb1, h2_w, h2_b, hg2, hb2, h3_w, h3_b, out);
  copyx_kernel<<<2048,256,0,stream>>>(XM, out);
}

// Round 7
// 6170.370 us; speedup vs baseline: 2.3542x; 1.3928x over previous
//
#include <hip/hip_runtime.h>
#include <math.h>

#define ACT_NONE 0
#define ACT_GELU 1
#define ACT_SOFTPLUS 2

template<int ACT>
__device__ __forceinline__ float act_apply(float x){
  if (ACT == ACT_GELU)     return 0.5f * x * (1.0f + erff(x * 0.70710678118654752f));
  if (ACT == ACT_SOFTPLUS) return fmaxf(x, 0.0f) + log1pf(expf(-fabsf(x)));
  return x;
}

// ---------------- bf16 split helpers ----------------
__device__ __forceinline__ unsigned short f2bf(float x){
  unsigned u = __float_as_uint(x);
  u = u + 0x7FFFu + ((u >> 16) & 1u);
  return (unsigned short)(u >> 16);
}
__device__ __forceinline__ float bf2f(unsigned short b){
  return __uint_as_float(((unsigned)b) << 16);
}
__device__ __forceinline__ void bfsplit(float x, unsigned short &hi, unsigned short &lo){
  hi = f2bf(x);
  lo = f2bf(x - bf2f(hi));
}

typedef __attribute__((ext_vector_type(8))) short v8s;
typedef __attribute__((ext_vector_type(4))) float v4f;

// ---------------- bf16x2 MFMA GEMM: 128x128 tile, 256 thr (4 waves) ------------
// A [M][K] bf16 hi/lo; B TRANSPOSED [N][K] bf16 hi/lo.
// OUT: 0 = fp32 store (+bias), 2 = bf16-split store.
template<int ACT, int OUT>
__global__ __launch_bounds__(256) void gemm_bf16x2_kernel(
    const unsigned short* __restrict__ Ahi, const unsigned short* __restrict__ Alo,
    const unsigned short* __restrict__ Bhi, const unsigned short* __restrict__ Blo,
    const float* __restrict__ bias, float* __restrict__ C,
    unsigned short* __restrict__ Chi, unsigned short* __restrict__ Clo,
    int K, int lda, int ldb, int ldc)
{
  __shared__ unsigned short As[2][128][40];   // pad 40 shorts (20 words) -> 2-way max
  __shared__ unsigned short Bs[2][128][40];
  const int tid = threadIdx.x;
  const int m0 = blockIdx.y * 128;
  const int n0 = blockIdx.x * 128;
  const int w = tid >> 6, lane = tid & 63;
  const int wm = (w & 1) * 64, wn = (w >> 1) * 64;
  const int fm = lane & 15, fq = lane >> 4;
  const int r = tid >> 1, h = tid & 1;

  v4f acc[4][4];
#pragma unroll
  for (int i = 0; i < 4; i++)
#pragma unroll
    for (int j = 0; j < 4; j++) acc[i][j] = (v4f){0.f, 0.f, 0.f, 0.f};

  for (int k0 = 0; k0 < K; k0 += 32) {
    const uint4* gah = (const uint4*)(Ahi + (size_t)(m0 + r) * lda + k0 + h * 16);
    const uint4* gal = (const uint4*)(Alo + (size_t)(m0 + r) * lda + k0 + h * 16);
    const uint4* gbh = (const uint4*)(Bhi + (size_t)(n0 + r) * ldb + k0 + h * 16);
    const uint4* gbl = (const uint4*)(Blo + (size_t)(n0 + r) * ldb + k0 + h * 16);
    uint4 ah0 = gah[0], ah1 = gah[1];
    uint4 al0 = gal[0], al1 = gal[1];
    uint4 bh0 = gbh[0], bh1 = gbh[1];
    uint4 bl0 = gbl[0], bl1 = gbl[1];
    __syncthreads();
    *(uint4*)&As[0][r][h * 16]     = ah0;
    *(uint4*)&As[0][r][h * 16 + 8] = ah1;
    *(uint4*)&As[1][r][h * 16]     = al0;
    *(uint4*)&As[1][r][h * 16 + 8] = al1;
    *(uint4*)&Bs[0][r][h * 16]     = bh0;
    *(uint4*)&Bs[0][r][h * 16 + 8] = bh1;
    *(uint4*)&Bs[1][r][h * 16]     = bl0;
    *(uint4*)&Bs[1][r][h * 16 + 8] = bl1;
    __syncthreads();

    v8s ah[4], al[4];
#pragma unroll
    for (int i = 0; i < 4; i++) {
      ah[i] = *(const v8s*)&As[0][wm + i * 16 + fm][fq * 8];
      al[i] = *(const v8s*)&As[1][wm + i * 16 + fm][fq * 8];
    }
#pragma unroll
    for (int j = 0; j < 4; j++) {
      v8s bh = *(const v8s*)&Bs[0][wn + j * 16 + fm][fq * 8];
      v8s bl = *(const v8s*)&Bs[1][wn + j * 16 + fm][fq * 8];
#pragma unroll
      for (int i = 0; i < 4; i++) {
        acc[i][j] = __builtin_amdgcn_mfma_f32_16x16x32_bf16(ah[i], bh, acc[i][j], 0, 0, 0);
        acc[i][j] = __builtin_amdgcn_mfma_f32_16x16x32_bf16(ah[i], bl, acc[i][j], 0, 0, 0);
        acc[i][j] = __builtin_amdgcn_mfma_f32_16x16x32_bf16(al[i], bh, acc[i][j], 0, 0, 0);
      }
    }
  }

#pragma unroll
  for (int i = 0; i < 4; i++)
#pragma unroll
    for (int j = 0; j < 4; j++) {
      int col = n0 + wn + j * 16 + fm;
      float bv = bias ? bias[col] : 0.0f;
#pragma unroll
      for (int reg = 0; reg < 4; reg++) {
        int row = m0 + wm + i * 16 + fq * 4 + reg;
        float v = acc[i][j][reg] + bv;
        v = act_apply<ACT>(v);
        size_t idx = (size_t)row * ldc + col;
        if (OUT == 0) C[idx] = v;
        else { unsigned short hi, lo; bfsplit(v, hi, lo); Chi[idx] = hi; Clo[idx] = lo; }
      }
    }
}

// ------- fused GEMM(bf16x2) + residual + LayerNorm + split write ---------------
// tile 32 rows x 256 cols (full width), 256 thr, wave = 64-col group.
// X <- LN(X + A@B + bias) * g + beta   (X stored as hi/lo bf16 pair, in-place)
// R6 fix: no registers live across barriers (was spilling 250 MB/dispatch),
// coalesced B staging (4 lanes per row), LN computed in-place on acc.
__global__ __launch_bounds__(256) void gemm_ln_kernel(
    const unsigned short* __restrict__ Ahi, const unsigned short* __restrict__ Alo,
    const unsigned short* __restrict__ Bhi, const unsigned short* __restrict__ Blo,
    const float* __restrict__ bias,
    const float* __restrict__ g, const float* __restrict__ beta,
    unsigned short* __restrict__ Xhi, unsigned short* __restrict__ Xlo,
    int K, int lda, int ldb)
{
  __shared__ unsigned short As[2][32][40];
  __shared__ unsigned short Bs[2][256][40];
  __shared__ float rs[32][5];
  __shared__ float ms[32][2];
  const int tid = threadIdx.x;
  const int m0 = blockIdx.x * 32;
  const int w = tid >> 6, lane = tid & 63;
  const int fm = lane & 15, fq = lane >> 4;
  // A staging: 256 uint4 slots = 2 halves x 32 rows x 4 chunks
  const int a_sel = tid >> 7;
  const int a_row = (tid >> 2) & 31;
  const int a_c   = tid & 3;
  // B staging: per pass p: row = p*64 + (tid>>2), chunk = tid&3 (coalesced 64B/row)
  const int b_row = tid >> 2;
  const int b_c   = tid & 3;

  v4f acc[2][4];
#pragma unroll
  for (int i = 0; i < 2; i++)
#pragma unroll
    for (int j = 0; j < 4; j++) acc[i][j] = (v4f){0.f, 0.f, 0.f, 0.f};

  for (int k0 = 0; k0 < K; k0 += 32) {
    __syncthreads();   // previous compute done before LDS overwrite
    {
      const unsigned short* asrc = (a_sel ? Alo : Ahi) + (size_t)(m0 + a_row) * lda + k0 + a_c * 8;
      *(uint4*)&As[a_sel][a_row][a_c * 8] = *(const uint4*)asrc;
    }
#pragma unroll
    for (int p = 0; p < 4; p++) {
      int row = p * 64 + b_row;
      *(uint4*)&Bs[0][row][b_c * 8] = *(const uint4*)(Bhi + (size_t)row * ldb + k0 + b_c * 8);
      *(uint4*)&Bs[1][row][b_c * 8] = *(const uint4*)(Blo + (size_t)row * ldb + k0 + b_c * 8);
    }
    __syncthreads();

    v8s ah[2], al[2];
#pragma unroll
    for (int i = 0; i < 2; i++) {
      ah[i] = *(const v8s*)&As[0][i * 16 + fm][fq * 8];
      al[i] = *(const v8s*)&As[1][i * 16 + fm][fq * 8];
    }
#pragma unroll
    for (int j = 0; j < 4; j++) {
      v8s bhf = *(const v8s*)&Bs[0][w * 64 + j * 16 + fm][fq * 8];
      v8s blf = *(const v8s*)&Bs[1][w * 64 + j * 16 + fm][fq * 8];
#pragma unroll
      for (int i = 0; i < 2; i++) {
        acc[i][j] = __builtin_amdgcn_mfma_f32_16x16x32_bf16(ah[i], bhf, acc[i][j], 0, 0, 0);
        acc[i][j] = __builtin_amdgcn_mfma_f32_16x16x32_bf16(ah[i], blf, acc[i][j], 0, 0, 0);
        acc[i][j] = __builtin_amdgcn_mfma_f32_16x16x32_bf16(al[i], bhf, acc[i][j], 0, 0, 0);
      }
    }
  }

  // acc <- x_old + delta + bias  (in place; no extra register array)
#pragma unroll
  for (int i = 0; i < 2; i++)
#pragma unroll
    for (int j = 0; j < 4; j++) {
      int cl = w * 64 + j * 16 + fm;
      float bv = bias[cl];
#pragma unroll
      for (int reg = 0; reg < 4; reg++) {
        int rl = i * 16 + fq * 4 + reg;
        size_t idx = (size_t)(m0 + rl) * 256 + cl;
        acc[i][j][reg] += bv + bf2f(Xhi[idx]) + bf2f(Xlo[idx]);
      }
    }
  // pass 1: mean
#pragma unroll
  for (int i = 0; i < 2; i++)
#pragma unroll
    for (int reg = 0; reg < 4; reg++) {
      float s = acc[i][0][reg] + acc[i][1][reg] + acc[i][2][reg] + acc[i][3][reg];
      s += __shfl_xor(s, 1); s += __shfl_xor(s, 2);
      s += __shfl_xor(s, 4); s += __shfl_xor(s, 8);
      if (fm == 0) rs[i * 16 + fq * 4 + reg][w] = s;
    }
  __syncthreads();
  if (tid < 32) ms[tid][0] = (rs[tid][0] + rs[tid][1] + rs[tid][2] + rs[tid][3]) * (1.0f / 256.0f);
  __syncthreads();
  // pass 2: var
#pragma unroll
  for (int i = 0; i < 2; i++)
#pragma unroll
    for (int reg = 0; reg < 4; reg++) {
      int rl = i * 16 + fq * 4 + reg;
      float mean = ms[rl][0];
      float s = 0.0f;
#pragma unroll
      for (int j = 0; j < 4; j++) { float d = acc[i][j][reg] - mean; s += d * d; }
      s += __shfl_xor(s, 1); s += __shfl_xor(s, 2);
      s += __shfl_xor(s, 4); s += __shfl_xor(s, 8);
      if (fm == 0) rs[rl][w] = s;
    }
  __syncthreads();
  if (tid < 32) {
    float var = (rs[tid][0] + rs[tid][1] + rs[tid][2] + rs[tid][3]) * (1.0f / 256.0f);
    ms[tid][1] = rsqrtf(var + 1e-5f);
  }
  __syncthreads();
#pragma unroll
  for (int i = 0; i < 2; i++)
#pragma unroll
    for (int j = 0; j < 4; j++) {
      int cl = w * 64 + j * 16 + fm;
      float gv = g[cl], bv = beta[cl];
#pragma unroll
      for (int reg = 0; reg < 4; reg++) {
        int rl = i * 16 + fq * 4 + reg;
        float t = (acc[i][j][reg] - ms[rl][0]) * ms[rl][1] * gv + bv;
        size_t idx = (size_t)(m0 + rl) * 256 + cl;
        unsigned short hi, lo; bfsplit(t, hi, lo);
        Xhi[idx] = hi; Xlo[idx] = lo;
      }
    }
}

// -------- weight transpose + split (batched over layers via blockIdx.z) --------
__global__ __launch_bounds__(256) void wsplit_kernel(
    const float* __restrict__ W, unsigned short* __restrict__ Whi,
    unsigned short* __restrict__ Wlo, int K, int N, size_t wstride, size_t ostride)
{
  __shared__ float tile[32][33];
  const float* Wl = W + blockIdx.z * wstride;
  unsigned short* Whl = Whi + blockIdx.z * ostride;
  unsigned short* Wll = Wlo + blockIdx.z * ostride;
  int k0 = blockIdx.y * 32, n0 = blockIdx.x * 32;
  int t = threadIdx.x;
  int tn = t & 31, tk8 = t >> 5;
#pragma unroll
  for (int i = 0; i < 4; i++) {
    int k = tk8 + i * 8;
    tile[k][tn] = Wl[(size_t)(k0 + k) * N + n0 + tn];
  }
  __syncthreads();
  int tk = t & 31, tn8 = t >> 5;
#pragma unroll
  for (int i = 0; i < 4; i++) {
    int n = tn8 + i * 8;
    float v = tile[tk][n];
    unsigned short hi, lo; bfsplit(v, hi, lo);
    size_t idx = (size_t)(n0 + n) * K + k0 + tk;
    Whl[idx] = hi; Wll[idx] = lo;
  }
}

// ------------- fp32 GEMM 128x128 (embed only), POS + split write ---------------
template<int ACT, int POS, int SPLIT>
__global__ __launch_bounds__(256) void gemm128_kernel(
    const float* __restrict__ A, const float* __restrict__ W,
    const float* __restrict__ bias, const float* __restrict__ pos,
    float* __restrict__ C, unsigned short* __restrict__ Chi, unsigned short* __restrict__ Clo,
    int K, int lda, int ldw, int ldc)
{
  __shared__ float As[16][128];
  __shared__ float Ws[16][128];
  const int tid = threadIdx.x;
  const int m0 = blockIdx.y * 128;
  const int n0 = blockIdx.x * 128;
  const int tx = tid & 15, ty = tid >> 4;
  const int ar = tid >> 2, ak = (tid & 3) * 4;
  const int wk = tid >> 5, wn = (tid & 31) * 4;

  float acc[8][8];
#pragma unroll
  for (int i = 0; i < 8; i++)
#pragma unroll
    for (int j = 0; j < 8; j++) acc[i][j] = 0.0f;

  for (int k0 = 0; k0 < K; k0 += 16) {
    float4 a0 = *(const float4*)(A + (size_t)(m0 + ar)      * lda + k0 + ak);
    float4 a1 = *(const float4*)(A + (size_t)(m0 + ar + 64) * lda + k0 + ak);
    float4 w0 = *(const float4*)(W + (size_t)(k0 + wk)     * ldw + n0 + wn);
    float4 w1 = *(const float4*)(W + (size_t)(k0 + wk + 8) * ldw + n0 + wn);
    __syncthreads();
    As[ak + 0][ar] = a0.x; As[ak + 1][ar] = a0.y; As[ak + 2][ar] = a0.z; As[ak + 3][ar] = a0.w;
    As[ak + 0][ar + 64] = a1.x; As[ak + 1][ar + 64] = a1.y; As[ak + 2][ar + 64] = a1.z; As[ak + 3][ar + 64] = a1.w;
    *(float4*)&Ws[wk][wn] = w0;
    *(float4*)&Ws[wk + 8][wn] = w1;
    __syncthreads();
#pragma unroll
    for (int k = 0; k < 16; k++) {
      float4 xa = *(float4*)&As[k][ty * 8];
      float4 xb = *(float4*)&As[k][ty * 8 + 4];
      float4 y0 = *(float4*)&Ws[k][tx * 8];
      float4 y1 = *(float4*)&Ws[k][tx * 8 + 4];
      float a8[8] = {xa.x, xa.y, xa.z, xa.w, xb.x, xb.y, xb.z, xb.w};
      float b8[8] = {y0.x, y0.y, y0.z, y0.w, y1.x, y1.y, y1.z, y1.w};
#pragma unroll
      for (int i = 0; i < 8; i++)
#pragma unroll
        for (int j = 0; j < 8; j++) acc[i][j] = fmaf(a8[i], b8[j], acc[i][j]);
    }
  }
#pragma unroll
  for (int i = 0; i < 8; i++) {
    int row = m0 + ty * 8 + i;
    float* cp = C + (size_t)row * ldc + n0 + tx * 8;
    float v[8];
#pragma unroll
    for (int j = 0; j < 8; j++) {
      float t = acc[i][j];
      int col = n0 + tx * 8 + j;
      if (bias) t += bias[col];
      if (POS)  t += pos[(row & 63) * 256 + col];
      t = act_apply<ACT>(t);
      v[j] = t;
      if (SPLIT) {
        unsigned short hi, lo; bfsplit(t, hi, lo);
        size_t idx = (size_t)row * ldc + col;
        Chi[idx] = hi; Clo[idx] = lo;
      }
    }
    *(float4*)cp       = make_float4(v[0], v[1], v[2], v[3]);
    *(float4*)(cp + 4) = make_float4(v[4], v[5], v[6], v[7]);
  }
}

// ---------------- GEMM 64x64 tile fp32 (mamba) ----------------
template<int ACT>
__global__ __launch_bounds__(256) void gemm64_kernel(
    const float* __restrict__ A, const float* __restrict__ W,
    const float* __restrict__ bias, float* __restrict__ C,
    int K, int lda, int ldw, int ldc)
{
  __shared__ float As[16][64];
  __shared__ float Ws[16][64];
  const int tid = threadIdx.x;
  const int m0 = blockIdx.y * 64;
  const int n0 = blockIdx.x * 64;
  const int tx = tid & 15, ty = tid >> 4;
  const int ar = tid >> 2, ak = (tid & 3) * 4;
  const int wk = tid >> 4, wn = (tid & 15) * 4;

  float acc[4][4];
#pragma unroll
  for (int i = 0; i < 4; i++)
#pragma unroll
    for (int j = 0; j < 4; j++) acc[i][j] = 0.0f;

  for (int k0 = 0; k0 < K; k0 += 16) {
    float4 a0 = *(const float4*)(A + (size_t)(m0 + ar) * lda + k0 + ak);
    float4 w0 = *(const float4*)(W + (size_t)(k0 + wk) * ldw + n0 + wn);
    __syncthreads();
    As[ak + 0][ar] = a0.x; As[ak + 1][ar] = a0.y; As[ak + 2][ar] = a0.z; As[ak + 3][ar] = a0.w;
    *(float4*)&Ws[wk][wn] = w0;
    __syncthreads();
#pragma unroll
    for (int k = 0; k < 16; k++) {
      float4 xa = *(float4*)&As[k][ty * 4];
      float4 yb = *(float4*)&Ws[k][tx * 4];
      float a4[4] = {xa.x, xa.y, xa.z, xa.w};
      float b4[4] = {yb.x, yb.y, yb.z, yb.w};
#pragma unroll
      for (int i = 0; i < 4; i++)
#pragma unroll
        for (int j = 0; j < 4; j++) acc[i][j] = fmaf(a4[i], b4[j], acc[i][j]);
    }
  }
#pragma unroll
  for (int i = 0; i < 4; i++) {
    float* cp = C + (size_t)(m0 + ty * 4 + i) * ldc + n0 + tx * 4;
    float v[4];
#pragma unroll
    for (int j = 0; j < 4; j++) {
      float t = acc[i][j];
      if (bias) t += bias[n0 + tx * 4 + j];
      v[j] = act_apply<ACT>(t);
    }
    *(float4*)cp = make_float4(v[0], v[1], v[2], v[3]);
  }
}

// ---------------- fused attention; writes bf16-split AT ----------------
__global__ __launch_bounds__(64) void attn_fused_kernel(
    const float* __restrict__ QKVc, const float* __restrict__ mask,
    unsigned short* __restrict__ AThi, unsigned short* __restrict__ ATlo, int n0)
{
  int bid = blockIdx.x;
  int nl = bid >> 3;
  int h = bid & 7;
  int n = n0 + nl;
  int tid = threadIdx.x;
  int tx = tid & 7, ty = tid >> 3;
  __shared__ float Qt[32][68];
  __shared__ float Kt[32][68];
  __shared__ float Vs[64][36];
  __shared__ float Pt[64][68];
  __shared__ float bs[64];
  const float* base = QKVc + (size_t)nl * (64 * 768);
#pragma unroll
  for (int i = 0; i < 32; i++) {
    int idx = tid + i * 64;
    int bar = idx >> 5, c = idx & 31;
    Qt[c][bar] = base[bar * 768 + h * 32 + c];
    Kt[c][bar] = base[bar * 768 + 256 + h * 32 + c];
    Vs[bar][c] = base[bar * 768 + 512 + h * 32 + c];
  }
  bs[tid] = (1.0f - mask[n * 64 + tid]) * -1e9f;
  __syncthreads();
  float acc[8][8] = {};
  for (int c = 0; c < 32; c++) {
    float4 ax = *(float4*)&Qt[c][ty * 8];
    float4 ay = *(float4*)&Qt[c][ty * 8 + 4];
    float4 bx = *(float4*)&Kt[c][tx * 8];
    float4 by = *(float4*)&Kt[c][tx * 8 + 4];
    float a8[8] = {ax.x, ax.y, ax.z, ax.w, ay.x, ay.y, ay.z, ay.w};
    float b8[8] = {bx.x, bx.y, bx.z, bx.w, by.x, by.y, by.z, by.w};
#pragma unroll
    for (int i = 0; i < 8; i++)
#pragma unroll
      for (int j = 0; j < 8; j++) acc[i][j] = fmaf(a8[i], b8[j], acc[i][j]);
  }
  const float scale = 0.17677669529663687f;
#pragma unroll
  for (int i = 0; i < 8; i++) {
    float s[8];
    float mx = -3.0e38f;
#pragma unroll
    for (int j = 0; j < 8; j++) { s[j] = acc[i][j] * scale + bs[tx * 8 + j]; mx = fmaxf(mx, s[j]); }
#pragma unroll
    for (int off = 1; off < 8; off <<= 1) mx = fmaxf(mx, __shfl_xor(mx, off));
    float sum = 0.0f;
#pragma unroll
    for (int j = 0; j < 8; j++) { s[j] = expf(s[j] - mx); sum += s[j]; }
#pragma unroll
    for (int off = 1; off < 8; off <<= 1) sum += __shfl_xor(sum, off);
    float inv = 1.0f / sum;
#pragma unroll
    for (int j = 0; j < 8; j++) Pt[tx * 8 + j][ty * 8 + i] = s[j] * inv;
  }
  __syncthreads();
  float o[8][4] = {};
  for (int j = 0; j < 64; j++) {
    float4 px = *(float4*)&Pt[j][ty * 8];
    float4 py = *(float4*)&Pt[j][ty * 8 + 4];
    float4 v  = *(float4*)&Vs[j][tx * 4];
    float p8[8] = {px.x, px.y, px.z, px.w, py.x, py.y, py.z, py.w};
#pragma unroll
    for (int i = 0; i < 8; i++) {
      o[i][0] = fmaf(p8[i], v.x, o[i][0]);
      o[i][1] = fmaf(p8[i], v.y, o[i][1]);
      o[i][2] = fmaf(p8[i], v.z, o[i][2]);
      o[i][3] = fmaf(p8[i], v.w, o[i][3]);
    }
  }
#pragma unroll
  for (int i = 0; i < 8; i++) {
    size_t base_o = (size_t)(nl * 64 + ty * 8 + i) * 256 + h * 32 + tx * 4;
#pragma unroll
    for (int c = 0; c < 4; c++) {
      unsigned short hi, lo; bfsplit(o[i][c], hi, lo);
      AThi[base_o + c] = hi; ATlo[base_o + c] = lo;
    }
  }
}

// ---------------- LayerNorm wave-per-row (mamba): o = LN(a)*g+beta + b ----------
__global__ __launch_bounds__(256) void ln_res_kernel(
    const float* __restrict__ a, const float* __restrict__ b,
    const float* __restrict__ g, const float* __restrict__ beta,
    float* __restrict__ o, int Wd)
{
  int wave = threadIdx.x >> 6;
  int lane = threadIdx.x & 63;
  int row = blockIdx.x * 4 + wave;
  int P = Wd >> 6;
  const float* ar = a + (size_t)row * Wd;
  const float* br = b + (size_t)row * Wd;
  float v[8];
  float s = 0.0f;
  for (int i = 0; i < P; i++) { float x = ar[lane + i * 64]; v[i] = x; s += x; }
#pragma unroll
  for (int off = 32; off; off >>= 1) s += __shfl_xor(s, off);
  float mean = s / Wd;
  float vs = 0.0f;
  for (int i = 0; i < P; i++) { float d = v[i] - mean; vs += d * d; }
#pragma unroll
  for (int off = 32; off; off >>= 1) vs += __shfl_xor(vs, off);
  float rstd = rsqrtf(vs / Wd + 1e-5f);
  for (int i = 0; i < P; i++) {
    int col = lane + i * 64;
    o[(size_t)row * Wd + col] = (v[i] - mean) * rstd * g[col] + beta[col] + br[col];
  }
}

// ------------- masked mean over bars (reads hi/lo X) ---------------------------
__global__ __launch_bounds__(256) void mean_kernel(
    const unsigned short* __restrict__ Xhi, const unsigned short* __restrict__ Xlo,
    const float* __restrict__ mask, float* __restrict__ FE, int n0)
{
  int n = blockIdx.x;
  int c = threadIdx.x;
  float s = 0.0f, ms = 0.0f;
  for (int bar = 0; bar < 64; bar++) {
    float mk = mask[(n0 + n) * 64 + bar];
    size_t idx = (size_t)(n * 64 + bar) * 256 + c;
    s = fmaf(bf2f(Xhi[idx]) + bf2f(Xlo[idx]), mk, s);
    ms += mk;
  }
  FE[(n0 + n) * 256 + c] = s / fmaxf(ms, 1.0f);
}

// ---------------- mamba conv (4-tap causal) + silu ----------------
__global__ __launch_bounds__(256) void conv_kernel(
    const float* __restrict__ XZ, const float* __restrict__ w,
    const float* __restrict__ b, float* __restrict__ XC)
{
  int idx = blockIdx.x * 256 + threadIdx.x;
  int t = idx >> 10, c = idx & 1023;
  float acc = b[c];
  const float* wc = w + c * 4;
#pragma unroll
  for (int k = 0; k < 4; k++) {
    int tt = t + k - 3;
    if (tt >= 0) acc = fmaf(XZ[(size_t)tt * 2048 + c], wc[k], acc);
  }
  XC[idx] = acc / (1.0f + expf(-acc));
}

// ---------------- chunked scan (32 chunks x 32 steps) ----------------
#define NCH 32
#define CLEN 32

__global__ __launch_bounds__(256) void scan1_kernel(
    const float* __restrict__ DT, const float* __restrict__ XC,
    const float* __restrict__ XDBL, const float* __restrict__ Alog,
    float* __restrict__ HEND, float* __restrict__ PPR)
{
  int j = blockIdx.x >> 2;
  int c = (blockIdx.x & 3) * 256 + threadIdx.x;
  int t0 = j * CLEN;
  __shared__ float Bs[CLEN][16];
  for (int i = threadIdx.x; i < CLEN * 16; i += 256) {
    int r = i >> 4, s = i & 15;
    Bs[r][s] = XDBL[(t0 + r) * 64 + 32 + s];
  }
  float A[16], h[16], Pp[16];
#pragma unroll
  for (int s = 0; s < 16; s++) {
    A[s] = -expf(Alog[c * 16 + s]);
    h[s] = 0.0f; Pp[s] = 1.0f;
  }
  __syncthreads();
  for (int tt = 0; tt < CLEN; tt++) {
    int t = t0 + tt;
    float dtv = DT[(size_t)t * 1024 + c];
    float u = dtv * XC[(size_t)t * 1024 + c];
#pragma unroll
    for (int s = 0; s < 16; s++) {
      float e = expf(dtv * A[s]);
      h[s] = fmaf(h[s], e, u * Bs[tt][s]);
      Pp[s] *= e;
    }
  }
#pragma unroll
  for (int s = 0; s < 16; s++) {
    HEND[(size_t)(j * 1024 + c) * 16 + s] = h[s];
    PPR [(size_t)(j * 1024 + c) * 16 + s] = Pp[s];
  }
}

__global__ __launch_bounds__(256) void scan2_kernel(
    const float* __restrict__ HEND, const float* __restrict__ PPR, float* __restrict__ CIN)
{
  int id = blockIdx.x * 256 + threadIdx.x;
  float carry = 0.0f;
  for (int j = 0; j < NCH; j++) {
    CIN[j * 16384 + id] = carry;
    carry = fmaf(PPR[j * 16384 + id], carry, HEND[j * 16384 + id]);
  }
}

__global__ __launch_bounds__(256) void scan3_kernel(
    const float* __restrict__ DT, const float* __restrict__ XC,
    const float* __restrict__ XDBL, const float* __restrict__ Alog,
    const float* __restrict__ CIN, const float* __restrict__ mD,
    const float* __restrict__ XZ, float* __restrict__ Y)
{
  int j = blockIdx.x >> 2;
  int c = (blockIdx.x & 3) * 256 + threadIdx.x;
  int t0 = j * CLEN;
  __shared__ float Bs[CLEN][16], Cs[CLEN][16];
  for (int i = threadIdx.x; i < CLEN * 16; i += 256) {
    int r = i >> 4, s = i & 15;
    Bs[r][s] = XDBL[(t0 + r) * 64 + 32 + s];
    Cs[r][s] = XDBL[(t0 + r) * 64 + 48 + s];
  }
  float A[16], h[16];
#pragma unroll
  for (int s = 0; s < 16; s++) {
    A[s] = -expf(Alog[c * 16 + s]);
    h[s] = CIN[(size_t)(j * 1024 + c) * 16 + s];
  }
  float dval = mD[c];
  __syncthreads();
  for (int tt = 0; tt < CLEN; tt++) {
    int t = t0 + tt;
    float dtv = DT[(size_t)t * 1024 + c];
    float xcv = XC[(size_t)t * 1024 + c];
    float u = dtv * xcv;
    float y = 0.0f;
#pragma unroll
    for (int s = 0; s < 16; s++) {
      float e = expf(dtv * A[s]);
      h[s] = fmaf(h[s], e, u * Bs[tt][s]);
      y = fmaf(h[s], Cs[tt][s], y);
    }
    float z = XZ[(size_t)t * 2048 + 1024 + c];
    float sz = z / (1.0f + expf(-z));
    Y[(size_t)t * 1024 + c] = (y + dval * xcv) * sz;
  }
}

// ---------------- pooling + head ----------------
__global__ __launch_bounds__(1024) void pool1_kernel(
    const float* __restrict__ XM, const float* __restrict__ pw,
    const float* __restrict__ pb, float* __restrict__ PW)
{
  int t = threadIdx.x;
  float s = pb[0];
  for (int i = 0; i < 512; i++) s = fmaf(XM[(size_t)t * 512 + i], pw[i], s);
  __shared__ float red[1024];
  red[t] = s;
  __syncthreads();
  for (int off = 512; off > 0; off >>= 1) {
    if (t < off) red[t] = fmaxf(red[t], red[t + off]);
    __syncthreads();
  }
  float mx = red[0];
  __syncthreads();
  float e = expf(s - mx);
  red[t] = e;
  __syncthreads();
  for (int off = 512; off > 0; off >>= 1) {
    if (t < off) red[t] = red[t] + red[t + off];
    __syncthreads();
  }
  PW[t] = e / red[0];
}

__global__ __launch_bounds__(256) void pool2_kernel(
    const float* __restrict__ XM, const float* __restrict__ PW, float* __restrict__ HP)
{
  int hcol = blockIdx.x * 256 + threadIdx.x;
  float s = 0.0f;
  for (int tn = 0; tn < 1024; tn++) s = fmaf(PW[tn], XM[(size_t)tn * 512 + hcol], s);
  HP[hcol] = s;
}

__device__ __forceinline__ float blk_reduce_sum_128(float v, float* red){
  int t = threadIdx.x;
#pragma unroll
  for (int off = 32; off; off >>= 1) v += __shfl_xor(v, off);
  __syncthreads();
  if ((t & 63) == 0) red[t >> 6] = v;
  __syncthreads();
  return red[0] + red[1];
}

__global__ __launch_bounds__(128) void head_kernel(
    const float* __restrict__ HP, const float* __restrict__ h1w, const float* __restrict__ h1b,
    const float* __restrict__ g1, const float* __restrict__ be1,
    const float* __restrict__ h2w, const float* __restrict__ h2b,
    const float* __restrict__ g2, const float* __restrict__ be2,
    const float* __restrict__ h3w, const float* __restrict__ h3b,
    float* __restrict__ out)
{
  __shared__ float t1[128];
  __shared__ float red[2];
  int i = threadIdx.x;
  float s = h1b[i];
  for (int k = 0; k < 512; k++) s = fmaf(HP[k], h1w[k * 128 + i], s);
  float mean = blk_reduce_sum_128(s, red) * (1.0f / 128.0f);
  float d = s - mean;
  float var = blk_reduce_sum_128(d * d, red) * (1.0f / 128.0f);
  float x1 = d * rsqrtf(var + 1e-5f) * g1[i] + be1[i];
  x1 = 0.5f * x1 * (1.0f + erff(x1 * 0.70710678118654752f));
  t1[i] = x1;
  __syncthreads();
  s = h2b[i];
  for (int k = 0; k < 128; k++) s = fmaf(t1[k], h2w[k * 128 + i], s);
  mean = blk_reduce_sum_128(s, red) * (1.0f / 128.0f);
  d = s - mean;
  var = blk_reduce_sum_128(d * d, red) * (1.0f / 128.0f);
  float x2 = d * rsqrtf(var + 1e-5f) * g2[i] + be2[i];
  x2 = 0.5f * x2 * (1.0f + erff(x2 * 0.70710678118654752f));
  float tot = blk_reduce_sum_128(x2 * h3w[i], red);
  if (i == 0) out[0] = tot + h3b[0];
}

__global__ __launch_bounds__(256) void copyx_kernel(const float* __restrict__ XM, float* __restrict__ out){
  int i = blockIdx.x * 256 + threadIdx.x;
  out[1 + i] = XM[i];
}

// ---------------- launch ----------------
extern "C" void kernel_launch(void* const* d_in, const int* in_sizes, int n_in,
                              void* d_out, int out_size, void* d_ws, size_t ws_size,
                              hipStream_t stream)
{
  const float* frames   = (const float*)d_in[0];
  const float* fmask    = (const float*)d_in[1];
  const float* in_w     = (const float*)d_in[2];
  const float* in_b     = (const float*)d_in[3];
  const float* pos_emb  = (const float*)d_in[4];
  const float* qkv_w    = (const float*)d_in[5];
  const float* qkv_b    = (const float*)d_in[6];
  const float* ao_w     = (const float*)d_in[7];
  const float* ao_b     = (const float*)d_in[8];
  const float* ln1_g    = (const float*)d_in[9];
  const float* ln1_b    = (const float*)d_in[10];
  const float* ffn_w1   = (const float*)d_in[11];
  const float* ffn_b1   = (const float*)d_in[12];
  const float* ffn_w2   = (const float*)d_in[13];
  const float* ffn_b2   = (const float*)d_in[14];
  const float* ln2_g    = (const float*)d_in[15];
  const float* ln2_b    = (const float*)d_in[16];
  const float* proj_w   = (const float*)d_in[17];
  const float* proj_b   = (const float*)d_in[18];
  const float* m_in_w   = (const float*)d_in[19];
  const float* m_conv_w = (const float*)d_in[20];
  const float* m_conv_b = (const float*)d_in[21];
  const float* m_xproj_w= (const float*)d_in[22];
  const float* m_dt_w   = (const float*)d_in[23];
  const float* m_dt_b   = (const float*)d_in[24];
  const float* m_Alog   = (const float*)d_in[25];
  const float* m_D      = (const float*)d_in[26];
  const float* m_out_w  = (const float*)d_in[27];
  const float* m_ln_g   = (const float*)d_in[28];
  const float* m_ln_b   = (const float*)d_in[29];
  const float* pool_w   = (const float*)d_in[30];
  const float* pool_b   = (const float*)d_in[31];
  const float* h1_w     = (const float*)d_in[32];
  const float* h1_b     = (const float*)d_in[33];
  const float* hg1      = (const float*)d_in[34];
  const float* hb1      = (const float*)d_in[35];
  const float* h2_w     = (const float*)d_in[36];
  const float* h2_b     = (const float*)d_in[37];
  const float* hg2      = (const float*)d_in[38];
  const float* hb2      = (const float*)d_in[39];
  const float* h3_w     = (const float*)d_in[40];
  const float* h3_b     = (const float*)d_in[41];
  float* out = (float*)d_out;

  // ---- workspace layout (floats), total 24,906,752 = 99.6 MB ----
  float* ws = (float*)d_ws;
  float* B  = ws;
  float* QF = B;                                       // 12,582,912 floats
  unsigned short* AThi = (unsigned short*)(B + 12582912);  // 4,194,304 shorts
  unsigned short* ATlo = AThi + 4194304;
  unsigned short* MIDhi = (unsigned short*)B;              // 16,777,216 shorts
  unsigned short* MIDlo = MIDhi + 16777216;

  unsigned short* Xhi = (unsigned short*)(ws + 16777216);  // 4,194,304 shorts
  unsigned short* Xlo = Xhi + 4194304;

  unsigned short* Wqkv_hi = (unsigned short*)(ws + 20971520); // 786,432
  unsigned short* Wqkv_lo = Wqkv_hi + 786432;
  unsigned short* Wao_hi  = Wqkv_lo + 786432;    // 262,144
  unsigned short* Wao_lo  = Wao_hi + 262144;
  unsigned short* Wf1_hi  = Wao_lo + 262144;     // 1,048,576
  unsigned short* Wf1_lo  = Wf1_hi + 1048576;
  unsigned short* Wf2_hi  = Wf1_lo + 1048576;    // 1,048,576
  unsigned short* Wf2_lo  = Wf2_hi + 1048576;    // ends at ws + 24,117,248 floats

  float* FE = ws + 24117248;         //   262,144
  float* XM = FE + 262144;           //   524,288
  float* PW = XM + 524288;           //     2,048
  float* HP = PW + 2048;             //     1,024

  // mamba aliases overlay B
  float* XZ   = B;                 // 2,097,152 (1024x2048)
  float* XC   = B + 2097152;       // 1,048,576
  float* DT   = B + 3145728;       // 1,048,576
  float* XDBL = B + 4194304;       //    65,536
  float* Y    = B + 4259840;       // 1,048,576
  float* TMP  = B + 5308416;       //   524,288
  float* HEND = B + 5832704;       //   524,288
  float* PPR  = B + 6356992;       //   524,288
  float* CIN  = B + 6881280;       //   524,288

  // ---- weight prep: 4 batched launches (z = layer) ----
  wsplit_kernel<<<dim3(24,8,4),256,0,stream>>>(qkv_w, Wqkv_hi, Wqkv_lo, 256, 768, 196608, 196608);
  wsplit_kernel<<<dim3(8,8,4),256,0,stream>>>(ao_w, Wao_hi, Wao_lo, 256, 256, 65536, 65536);
  wsplit_kernel<<<dim3(32,8,4),256,0,stream>>>(ffn_w1, Wf1_hi, Wf1_lo, 256, 1024, 262144, 262144);
  wsplit_kernel<<<dim3(8,32,4),256,0,stream>>>(ffn_w2, Wf2_hi, Wf2_lo, 1024, 256, 262144, 262144);

  // ---- encoder: 4 chunks of 256 sequences (16384 rows) ----
  for (int ch = 0; ch < 4; ch++) {
    int n0 = ch * 256;
    const float* fch = frames + (size_t)n0 * 64 * 32;
    gemm128_kernel<ACT_NONE,1,1><<<dim3(2,128),256,0,stream>>>(
        fch, in_w, in_b, pos_emb, QF, Xhi, Xlo, 32, 32, 256, 256);
    for (int l = 0; l < 4; l++) {
      gemm_bf16x2_kernel<ACT_NONE,0><<<dim3(6,128),256,0,stream>>>(
          Xhi, Xlo, Wqkv_hi + l*196608, Wqkv_lo + l*196608, qkv_b + l*768,
          QF, nullptr, nullptr, 256, 256, 256, 768);
      attn_fused_kernel<<<2048,64,0,stream>>>(QF, fmask, AThi, ATlo, n0);
      gemm_ln_kernel<<<512,256,0,stream>>>(
          AThi, ATlo, Wao_hi + l*65536, Wao_lo + l*65536, ao_b + l*256,
          ln1_g + l*256, ln1_b + l*256, Xhi, Xlo, 256, 256, 256);
      gemm_bf16x2_kernel<ACT_GELU,2><<<dim3(8,128),256,0,stream>>>(
          Xhi, Xlo, Wf1_hi + l*262144, Wf1_lo + l*262144, ffn_b1 + l*1024,
          nullptr, MIDhi, MIDlo, 256, 256, 256, 1024);
      gemm_ln_kernel<<<512,256,0,stream>>>(
          MIDhi, MIDlo, Wf2_hi + l*262144, Wf2_lo + l*262144, ffn_b2 + l*256,
          ln2_g + l*256, ln2_b + l*256, Xhi, Xlo, 1024, 1024, 1024);
    }
    mean_kernel<<<256,256,0,stream>>>(Xhi, Xlo, fmask, FE, n0);
  }

  gemm64_kernel<ACT_NONE><<<dim3(8,16),256,0,stream>>>(FE, proj_w, proj_b, XM, 256, 256, 512, 512);

  for (int l = 0; l < 8; l++) {
    gemm64_kernel<ACT_NONE><<<dim3(32,16),256,0,stream>>>(
        XM, m_in_w + (size_t)l*512*2048, nullptr, XZ, 512, 512, 2048, 2048);
    conv_kernel<<<4096,256,0,stream>>>(XZ, m_conv_w + l*1024*4, m_conv_b + l*1024, XC);
    gemm64_kernel<ACT_NONE><<<dim3(1,16),256,0,stream>>>(
        XC, m_xproj_w + (size_t)l*1024*64, nullptr, XDBL, 1024, 1024, 64, 64);
    gemm64_kernel<ACT_SOFTPLUS><<<dim3(16,16),256,0,stream>>>(
        XDBL, m_dt_w + (size_t)l*32*1024, m_dt_b + l*1024, DT, 32, 64, 1024, 1024);
    scan1_kernel<<<128,256,0,stream>>>(DT, XC, XDBL, m_Alog + l*16384, HEND, PPR);
    scan2_kernel<<<64,256,0,stream>>>(HEND, PPR, CIN);
    scan3_kernel<<<128,256,0,stream>>>(DT, XC, XDBL, m_Alog + l*16384, CIN, m_D + l*1024, XZ, Y);
    gemm64_kernel<ACT_NONE><<<dim3(8,16),256,0,stream>>>(
        Y, m_out_w + (size_t)l*1024*512, nullptr, TMP, 1024, 1024, 512, 512);
    ln_res_kernel<<<256,256,0,stream>>>(TMP, XM, m_ln_g + l*512, m_ln_b + l*512, XM, 512);
  }

  pool1_kernel<<<1,1024,0,stream>>>(XM, pool_w, pool_b, PW);
  pool2_kernel<<<2,256,0,stream>>>(XM, PW, HP);
  head_kernel<<<1,128,0,stream>>>(HP, h1_w, h1_b, hg1, hb1, h2_w, h2_b, hg2, hb2, h3_w, h3_b, out);
  copyx_kernel<<<2048,256,0,stream>>>(XM, out);
}